// Round 11
// baseline (371.599 us; speedup 1.0000x reference)
//
#include <hip/hip_runtime.h>
#include <hip/hip_bf16.h>
#include <hip/hip_fp16.h>

// B=2, Cin=512, C=64, H=W=48, N=2304 spatial, 4608 total columns.
// R11 = R9 pipeline (217.1us, best) with launch-structure compaction:
//   - upsample EXACTLY as R9 (105984 blocks, nt stores)
//   - k_gap folded into k_se (block-local SA means)
//   - gcconv merged into attn launch; gcup+se merged into one launch
//   8 launches -> 6.

typedef __attribute__((ext_vector_type(8))) short short8;
typedef __attribute__((ext_vector_type(4))) float f32x4;

#define GLOAD_LDS(gsrc, ldst) \
  __builtin_amdgcn_global_load_lds((const __attribute__((address_space(1))) void*)(gsrc), \
                                   (__attribute__((address_space(3))) void*)(ldst), 16, 0, 0)

// ---------------- ws layout (float offsets) ----------------
static constexpr size_t OFF_P1 = 0;                       // [2][512]
static constexpr size_t OFF_P3 = OFF_P1 + 2*512;          // [2*9][512]
static constexpr size_t OFF_P5 = OFF_P3 + 18*512;         // [2*25][512]
static constexpr size_t OFF_G0 = OFF_P5 + 50*512;         // [2*1][64]
static constexpr size_t OFF_G1 = OFF_G0 + 2*64;           // [2*9][64]
static constexpr size_t OFF_G2 = OFF_G1 + 18*64;          // [2*25][64]
static constexpr size_t OFF_S  = OFF_G2 + 50*64;          // [2][64][2304] f32
static constexpr size_t OFF_Q  = OFF_S  + 294912;         // [2][8][2304] f32
static constexpr size_t OFF_K  = OFF_Q  + 36864;          // [2][8][2304] f32
static constexpr size_t OFF_V  = OFF_K  + 36864;          // bf16 [2][64][2304]
static constexpr size_t OFF_SA = OFF_V  + 294912;         // [2][64][2304] f32
static constexpr size_t OFF_GC = OFF_SA + 294912;         // [3][2][64][2304] f32
static constexpr size_t OFF_MEAN = OFF_GC + 3*294912;     // (unused now)
static constexpr size_t OFF_WGT  = OFF_MEAN + 512;        // [2][4][64]
static constexpr size_t OFF_Y0 = OFF_WGT + 512;           // [2][256][2304]
static constexpr size_t OFF_Y1 = OFF_Y0 + 1179648;        // [2][128][2304]
static constexpr size_t OFF_Y2 = OFF_Y1 + 589824;         // [2][64][2304]
static constexpr size_t OFF_Y3 = OFF_Y2 + 294912;         // [2][64][2304]

// ---------------- K1: adaptive pools (1,3,5) ----------------
__global__ __launch_bounds__(256) void k_pool(const float* __restrict__ x, float* __restrict__ wsp){
  __shared__ float pl[2304];
  __shared__ float red[4];
  int bc = blockIdx.x;            // b*512 + cin
  int b = bc >> 9, cin = bc & 511;
  const float* src = x + (size_t)bc * 2304;
  int t = threadIdx.x;
  float ls = 0.f;
  #pragma unroll
  for (int j = 0; j < 9; j++){ int i = t + j*256; float v = src[i]; pl[i] = v; ls += v; }
  #pragma unroll
  for (int o = 32; o; o >>= 1) ls += __shfl_xor(ls, o);
  if ((t & 63) == 0) red[t >> 6] = ls;
  __syncthreads();
  if (t == 0) wsp[OFF_P1 + (size_t)b*512 + cin] = (red[0]+red[1]+red[2]+red[3]) * (1.f/2304.f);
  if (t < 9){
    int ry = t/3, rx = t%3; float sm = 0.f;
    for (int yy = 0; yy < 16; yy++)
      for (int xx = 0; xx < 16; xx++) sm += pl[(ry*16+yy)*48 + rx*16+xx];
    wsp[OFF_P3 + ((size_t)b*9 + t)*512 + cin] = sm * (1.f/256.f);
  } else if (t < 34){
    int j = t - 9; int ry = j/5, rx = j%5;
    int hs = (ry*48)/5, he = ((ry+1)*48+4)/5, cs = (rx*48)/5, ce = ((rx+1)*48+4)/5;
    float sm = 0.f;
    for (int yy = hs; yy < he; yy++)
      for (int xx = cs; xx < ce; xx++) sm += pl[yy*48+xx];
    wsp[OFF_P5 + ((size_t)b*25 + j)*512 + cin] = sm / (float)((he-hs)*(ce-cs));
  }
}

// ---------------- K3: s = relu(Wgc3.x+b) + fused QKV ----------------
__global__ __launch_bounds__(256) void k_sgemm_qkv(const float* __restrict__ x,
    const float* __restrict__ w, const float* __restrict__ bias,
    const float* __restrict__ wq, const float* __restrict__ bq,
    const float* __restrict__ wk, const float* __restrict__ bk,
    const float* __restrict__ wv, const float* __restrict__ bv,
    float* __restrict__ wsp){
  __shared__ __align__(16) float wt[64][66];     // [k][row]
  __shared__ __align__(16) float xs[64][32];     // [k][col] staged X chunk
  __shared__ __align__(16) float s_lds[64][36];  // [chan][col]
  __shared__ float wq_lds[80][64];
  __shared__ float bqkv[80];
  int cb = blockIdx.x;
  int b = cb / 72, hw0 = (cb - b*72)*32;
  int tid = threadIdx.x;
  int wv_ = tid >> 6, lane = tid & 63;
  for (int i = tid; i < 5120; i += 256){
    int row = i >> 6, k = i & 63;
    wq_lds[row][k] = (row < 8) ? wq[(size_t)row*64 + k]
                   : (row < 16) ? wk[(size_t)(row-8)*64 + k]
                                : wv[(size_t)(row-16)*64 + k];
  }
  if (tid < 80) bqkv[tid] = (tid < 8) ? bq[tid] : (tid < 16) ? bk[tid-8] : bv[tid-16];
  int sr = tid >> 2, sseg = tid & 3;
  int cc0 = (tid & 7)*4, r0 = (tid >> 3)*2;
  const float* xb = x + (size_t)b*512*2304 + hw0;
  float acc[2][4] = {};
  for (int kc = 0; kc < 512; kc += 64){
    __syncthreads();
    {
      int rr0 = wv_*16 + (lane >> 3);
      const float* g0 = xb + (size_t)(kc + rr0)*2304 + (lane & 7)*4;
      const float* g1 = xb + (size_t)(kc + rr0 + 8)*2304 + (lane & 7)*4;
      GLOAD_LDS(g0, &xs[wv_*16][0]);
      GLOAD_LDS(g1, &xs[wv_*16 + 8][0]);
    }
    #pragma unroll
    for (int i = 0; i < 16; i += 4){
      float4 v = *(const float4*)(w + (size_t)sr*512 + kc + sseg*16 + i);
      wt[sseg*16+i+0][sr]=v.x; wt[sseg*16+i+1][sr]=v.y;
      wt[sseg*16+i+2][sr]=v.z; wt[sseg*16+i+3][sr]=v.w;
    }
    __syncthreads();
    #pragma unroll 4
    for (int k = 0; k < 64; k++){
      float2 wv2 = *(const float2*)&wt[k][r0];
      float4 xv = *(const float4*)&xs[k][cc0];
      acc[0][0]+=wv2.x*xv.x; acc[0][1]+=wv2.x*xv.y; acc[0][2]+=wv2.x*xv.z; acc[0][3]+=wv2.x*xv.w;
      acc[1][0]+=wv2.y*xv.x; acc[1][1]+=wv2.y*xv.y; acc[1][2]+=wv2.y*xv.z; acc[1][3]+=wv2.y*xv.w;
    }
  }
  #pragma unroll
  for (int i = 0; i < 2; i++){
    float bi = bias[r0+i];
    float4 o;
    o.x = fmaxf(acc[i][0]+bi, 0.f); o.y = fmaxf(acc[i][1]+bi, 0.f);
    o.z = fmaxf(acc[i][2]+bi, 0.f); o.w = fmaxf(acc[i][3]+bi, 0.f);
    *(float4*)(wsp + OFF_S + ((size_t)b*64 + r0+i)*2304 + hw0 + cc0) = o;
    *(float4*)&s_lds[r0+i][cc0] = o;
  }
  __syncthreads();
  int col = tid & 31, rgrp = tid >> 5;
  float a2[10];
  #pragma unroll
  for (int i = 0; i < 10; i++) a2[i] = bqkv[rgrp*10 + i];
  for (int k = 0; k < 64; k++){
    float sv = s_lds[k][col];
    #pragma unroll
    for (int i = 0; i < 10; i++) a2[i] += wq_lds[rgrp*10 + i][k]*sv;
  }
  __hip_bfloat16* Vb = reinterpret_cast<__hip_bfloat16*>(wsp + OFF_V);
  int hw = hw0 + col;
  #pragma unroll
  for (int i = 0; i < 10; i++){
    int r = rgrp*10 + i;
    if (r < 8)       wsp[OFF_Q + (size_t)b*18432 + (size_t)r*2304 + hw] = a2[i];
    else if (r < 16) wsp[OFF_K + (size_t)b*18432 + (size_t)(r-8)*2304 + hw] = a2[i];
    else             Vb[(size_t)b*147456 + (size_t)(r-16)*2304 + hw] = __float2bfloat16(a2[i]);
  }
}

// ---------------- LAUNCH C: attn (0..287) + gcconv (288..357) ----------------
struct AttnSmem {
  float qs[16][8];
  unsigned short plds[16][2312];
  float redM[4][16], redS[4][16];
  float tile[16][68];
};

__device__ void attn_body(char* smem_raw, int blk, float* __restrict__ wsp, const float* __restrict__ gamma){
  AttnSmem& s = *reinterpret_cast<AttnSmem*>(smem_raw);
  int mb = (blk % 144) * 16;
  int b  = blk / 144;
  int t = threadIdx.x;
  int w = t >> 6, lane = t & 63;
  int arow = lane & 15, kg = lane >> 4;
  const float* Qp = wsp + OFF_Q + (size_t)b*18432;
  const float* Kp = wsp + OFF_K + (size_t)b*18432;
  if (t < 128) s.qs[t>>3][t&7] = Qp[(size_t)(t&7)*2304 + mb + (t>>3)];
  __syncthreads();
  float k8[9][8];
  #pragma unroll
  for (int j = 0; j < 9; j++){
    int n = j*256 + t;
    #pragma unroll
    for (int c = 0; c < 8; c++) k8[j][c] = Kp[(size_t)c*2304 + n];
  }
  float mx[16], ssum[16];
  #pragma unroll
  for (int m = 0; m < 16; m++){
    float q0=s.qs[m][0], q1=s.qs[m][1], q2=s.qs[m][2], q3=s.qs[m][3];
    float q4=s.qs[m][4], q5=s.qs[m][5], q6=s.qs[m][6], q7=s.qs[m][7];
    float lmx = -1e30f, ls = 0.f;
    #pragma unroll
    for (int j = 0; j < 9; j++){
      float l = q0*k8[j][0]+q1*k8[j][1]+q2*k8[j][2]+q3*k8[j][3]
              + q4*k8[j][4]+q5*k8[j][5]+q6*k8[j][6]+q7*k8[j][7];
      __half hv = __float2half(l);
      s.plds[m][j*256 + t] = __half_as_ushort(hv);
      float mo = lmx;
      lmx = fmaxf(lmx, l);
      ls = ls*__expf(mo - lmx) + __expf(l - lmx);
    }
    mx[m] = lmx; ssum[m] = ls;
  }
  #pragma unroll
  for (int m = 0; m < 16; m++){
    float M = mx[m], S = ssum[m];
    #pragma unroll
    for (int off = 32; off; off >>= 1){
      float oM = __shfl_xor(M, off), oS = __shfl_xor(S, off);
      float nM = fmaxf(M, oM);
      S = S*__expf(M - nM) + oS*__expf(oM - nM);
      M = nM;
    }
    if (lane == 0){ s.redM[w][m] = M; s.redS[w][m] = S; }
  }
  __syncthreads();
  float Mf[16], invS[16];
  #pragma unroll
  for (int m = 0; m < 16; m++){
    float M0 = s.redM[0][m], M1 = s.redM[1][m], M2 = s.redM[2][m], M3 = s.redM[3][m];
    float M = fmaxf(fmaxf(M0, M1), fmaxf(M2, M3));
    float S = s.redS[0][m]*__expf(M0-M) + s.redS[1][m]*__expf(M1-M)
            + s.redS[2][m]*__expf(M2-M) + s.redS[3][m]*__expf(M3-M);
    Mf[m] = M; invS[m] = 1.f/S;
  }
  const short* Vb = (const short*)(wsp + OFF_V) + (size_t)b*147456 + (size_t)(w*16 + arow)*2304;
  f32x4 acc = {0.f, 0.f, 0.f, 0.f};
  for (int j = 0; j < 9; j++){
    int n = j*256 + t;
    #pragma unroll
    for (int m = 0; m < 16; m++){
      float l = __half2float(__ushort_as_half(s.plds[m][n]));
      float p = __expf(l - Mf[m]) * invS[m];
      __hip_bfloat16 pb = __float2bfloat16(p);
      s.plds[m][n] = *(unsigned short*)&pb;
    }
    __syncthreads();
    #pragma unroll
    for (int ks = 0; ks < 8; ks++){
      int nb = j*256 + ks*32 + kg*8;
      short8 a  = *(const short8*)&s.plds[arow][nb];
      short8 bv = *(const short8*)(Vb + nb);
      acc = __builtin_amdgcn_mfma_f32_16x16x32_bf16(a, bv, acc, 0, 0, 0);
    }
  }
  #pragma unroll
  for (int r = 0; r < 4; r++) s.tile[kg*4 + r][w*16 + arow] = acc[r];
  __syncthreads();
  int c = t >> 2, mq = t & 3;
  float g = gamma[0];
  const float* Sp = wsp + OFF_S + (size_t)b*147456 + (size_t)c*2304 + mb + mq*4;
  float4 s4 = *(const float4*)Sp;
  float4 o;
  o.x = g*s.tile[mq*4+0][c] + s4.x;
  o.y = g*s.tile[mq*4+1][c] + s4.y;
  o.z = g*s.tile[mq*4+2][c] + s4.z;
  o.w = g*s.tile[mq*4+3][c] + s4.w;
  *(float4*)(wsp + OFF_SA + (size_t)b*147456 + (size_t)c*2304 + mb + mq*4) = o;
}

__device__ void gcconv_body(int col,
    const float* __restrict__ w0, const float* __restrict__ b0,
    const float* __restrict__ w1, const float* __restrict__ b1,
    const float* __restrict__ w2, const float* __restrict__ b2,
    float* __restrict__ wsp){
  const float* w; const float* bias; const float* pool; float* dst;
  if (col < 2){ w = w0; bias = b0; pool = wsp + OFF_P1 + (size_t)col*512; dst = wsp + OFF_G0 + (size_t)col*64; }
  else if (col < 20){ int c = col-2;  w = w1; bias = b1; pool = wsp + OFF_P3 + (size_t)c*512; dst = wsp + OFF_G1 + (size_t)c*64; }
  else              { int c = col-20; w = w2; bias = b2; pool = wsp + OFF_P5 + (size_t)c*512; dst = wsp + OFF_G2 + (size_t)c*64; }
  int t = threadIdx.x; int r = t >> 2, qd = t & 3;
  const float* wr = w + (size_t)r*512 + qd*128;
  const float* pr = pool + qd*128;
  float acc = 0.f;
  #pragma unroll 8
  for (int k = 0; k < 128; k += 4){
    float4 wv = *(const float4*)(wr + k); float4 pv = *(const float4*)(pr + k);
    acc += wv.x*pv.x + wv.y*pv.y + wv.z*pv.z + wv.w*pv.w;
  }
  acc += __shfl_xor(acc, 1); acc += __shfl_xor(acc, 2);
  if (qd == 0) dst[r] = fmaxf(acc + bias[r], 0.f);
}

__global__ __launch_bounds__(256) void k_attn_gcconv(float* __restrict__ wsp, const float* __restrict__ gamma,
    const float* __restrict__ w0, const float* __restrict__ b0,
    const float* __restrict__ w1, const float* __restrict__ b1,
    const float* __restrict__ w2, const float* __restrict__ b2){
  __shared__ __align__(16) char smem[sizeof(AttnSmem)];
  int bx = blockIdx.x;
  if (bx < 288) attn_body(smem, bx, wsp, gamma);
  else          gcconv_body(bx - 288, w0, b0, w1, b1, w2, b2, wsp);
}

// ---------------- LAUNCH D: gcup (0..3455) + se w/ folded SA-mean (3456..3457) ----------------
__device__ void gcup_body(int u, float* __restrict__ wsp){
  int px = (u % 9)*256 + threadIdx.x;
  int pb = u / 9;
  int c = pb & 63, b = (pb >> 6) & 1, t = pb >> 7;
  int oy = px / 48, ox = px - oy*48;
  int ps; const float* g;
  if (t == 0){ ps = 1; g = wsp + OFF_G0 + (size_t)b*64; }
  else if (t == 1){ ps = 3; g = wsp + OFF_G1 + (size_t)b*9*64; }
  else { ps = 5; g = wsp + OFF_G2 + (size_t)b*25*64; }
  float scale = (ps - 1) / 47.f;
  float cy = oy*scale, cx = ox*scale;
  int y0 = (int)cy, x0 = (int)cx;
  float wy = cy - y0, wx = cx - x0;
  int y1 = min(y0+1, ps-1), x1 = min(x0+1, ps-1);
  float a  = g[(y0*ps+x0)*64 + c], bq = g[(y0*ps+x1)*64 + c];
  float cc = g[(y1*ps+x0)*64 + c], d  = g[(y1*ps+x1)*64 + c];
  float v = (a*(1.f-wx) + bq*wx)*(1.f-wy) + (cc*(1.f-wx) + d*wx)*wy;
  wsp[OFF_GC + (((size_t)t*2 + b)*64 + c)*2304 + px] = v;
}

__device__ void se_body(int b,
    const float* __restrict__ w_se1, const float* __restrict__ w_se2,
    const float* __restrict__ w_se3, const float* __restrict__ w_se4,
    float* __restrict__ wsp){
  __shared__ float msa[64];
  __shared__ float mean_lds[4][64];
  __shared__ float sh[4][64];
  int tid = threadIdx.x;
  int wv_ = tid >> 6, lane = tid & 63;
  // phase 1: SA channel means (replaces k_gap for this batch)
  for (int r = wv_; r < 64; r += 4){
    const float* src = wsp + OFF_SA + (size_t)b*147456 + (size_t)r*2304;
    float s = 0.f;
    for (int i = lane; i < 2304; i += 64) s += src[i];
    #pragma unroll
    for (int o = 32; o; o >>= 1) s += __shfl_xor(s, o);
    if (lane == 0) msa[r] = s * (1.f/2304.f);
  }
  __syncthreads();
  int g = tid >> 6, c = tid & 63;
  float mv;
  if (g == 0){
    mv = msa[c];
  } else if (g == 3){
    mv = wsp[OFF_G0 + (size_t)b*64 + c];
  } else if (g == 2){
    float w3[3] = {0.f,0.f,0.f};
    for (int o = 0; o < 48; o++){
      float cc = o*(2.f/47.f); int i0 = (int)cc; float f = cc - i0;
      int i1 = min(i0+1, 2);
      w3[i0] += 1.f - f; w3[i1] += f;
    }
    float s = 0.f;
    for (int sy = 0; sy < 3; sy++)
      for (int sx = 0; sx < 3; sx++)
        s += w3[sy]*w3[sx]*wsp[OFF_G1 + ((size_t)b*9 + sy*3 + sx)*64 + c];
    mv = s * (1.f/(48.f*48.f));
  } else {
    float w5[5] = {0.f,0.f,0.f,0.f,0.f};
    for (int o = 0; o < 48; o++){
      float cc = o*(4.f/47.f); int i0 = (int)cc; float f = cc - i0;
      int i1 = min(i0+1, 4);
      w5[i0] += 1.f - f; w5[i1] += f;
    }
    float s = 0.f;
    for (int sy = 0; sy < 5; sy++)
      for (int sx = 0; sx < 5; sx++)
        s += w5[sy]*w5[sx]*wsp[OFF_G2 + ((size_t)b*25 + sy*5 + sx)*64 + c];
    mv = s * (1.f/(48.f*48.f));
  }
  mean_lds[g][c] = mv;
  __syncthreads();
  const float* w = (g == 0) ? w_se1 : (g == 1) ? w_se2 : (g == 2) ? w_se3 : w_se4;
  float acc = 0.f;
  for (int j = 0; j < 64; j++) acc += w[(size_t)c*64 + j]*mean_lds[g][j];
  float sg = 1.f / (1.f + __expf(-acc));
  sh[g][c] = sg;
  __syncthreads();
  float a0 = sh[0][c], a1 = sh[1][c], a2 = sh[2][c], a3 = sh[3][c];
  float mxv = fmaxf(fmaxf(a0, a1), fmaxf(a2, a3));
  float e = __expf(sg - mxv);
  float sum = __expf(a0-mxv) + __expf(a1-mxv) + __expf(a2-mxv) + __expf(a3-mxv);
  wsp[OFF_WGT + ((size_t)b*4 + g)*64 + c] = e / sum;
}

__global__ __launch_bounds__(256) void k_gcup_se(float* __restrict__ wsp,
    const float* __restrict__ w_se1, const float* __restrict__ w_se2,
    const float* __restrict__ w_se3, const float* __restrict__ w_se4){
  int bx = blockIdx.x;
  if (bx < 3456) gcup_body(bx, wsp);
  else           se_body(bx - 3456, w_se1, w_se2, w_se3, w_se4, wsp);
}

// ---------------- K12: out-head GEMMs, wgt folded, X staged via global_load_lds ----------------
__global__ __launch_bounds__(256) void k_outgemm(
    const float* __restrict__ w0, const float* __restrict__ b0,
    const float* __restrict__ w1, const float* __restrict__ b1,
    const float* __restrict__ w2, const float* __restrict__ b2,
    const float* __restrict__ w3, const float* __restrict__ b3,
    float* __restrict__ wsp){
  __shared__ __align__(16) float wt[64][68];
  __shared__ __align__(16) float xsh[64][64];   // staged activation chunk (16 KB, linear)
  __shared__ float wg[256];
  int cb = blockIdx.x, rb = blockIdx.y;
  int b = cb / 36, hw0 = (cb - b*36)*64;
  const float* wsrc; const float* bsrc; size_t dstoff; int dstC; int row0;
  if (rb < 4){ wsrc = w0 + (size_t)rb*64*256; bsrc = b0 + rb*64; dstoff = OFF_Y0; dstC = 256; row0 = rb*64; }
  else if (rb < 6){ wsrc = w1 + (size_t)(rb-4)*64*256; bsrc = b1 + (rb-4)*64; dstoff = OFF_Y1; dstC = 128; row0 = (rb-4)*64; }
  else if (rb == 6){ wsrc = w2; bsrc = b2; dstoff = OFF_Y2; dstC = 64; row0 = 0; }
  else { wsrc = w3; bsrc = b3; dstoff = OFF_Y3; dstC = 64; row0 = 0; }
  int tid = threadIdx.x;
  int wv_ = tid >> 6, lane = tid & 63;
  wg[tid] = wsp[OFF_WGT + (size_t)b*256 + tid];
  int sr = tid >> 2, sseg = tid & 3;
  int cc0 = (tid & 15)*4, r0 = (tid >> 4)*4;
  float acc[4][4] = {};
  for (int kc = 0; kc < 256; kc += 64){
    __syncthreads();
    {
      int gidx = kc >> 6;
      size_t srcbase = (gidx < 3) ? OFF_GC + ((size_t)(gidx*2 + b))*147456
                                  : OFF_SA + (size_t)b*147456;
      const float* gb = wsp + srcbase + hw0 + (lane & 15)*4;
      int rr = wv_*16 + (lane >> 4);
      #pragma unroll
      for (int i = 0; i < 4; i++)
        GLOAD_LDS(gb + (size_t)(rr + i*4)*2304, &xsh[wv_*16 + i*4][0]);
    }
    #pragma unroll
    for (int i = 0; i < 16; i += 4){
      float4 v = *(const float4*)(wsrc + (size_t)sr*256 + kc + sseg*16 + i);
      int kl = sseg*16 + i;
      wt[kl+0][sr]=v.x*wg[kc+kl+0]; wt[kl+1][sr]=v.y*wg[kc+kl+1];
      wt[kl+2][sr]=v.z*wg[kc+kl+2]; wt[kl+3][sr]=v.w*wg[kc+kl+3];
    }
    __syncthreads();
    #pragma unroll 4
    for (int k = 0; k < 64; k++){
      float4 wv = *(const float4*)&wt[k][r0];
      float4 xv = *(const float4*)&xsh[k][cc0];
      acc[0][0]+=wv.x*xv.x; acc[0][1]+=wv.x*xv.y; acc[0][2]+=wv.x*xv.z; acc[0][3]+=wv.x*xv.w;
      acc[1][0]+=wv.y*xv.x; acc[1][1]+=wv.y*xv.y; acc[1][2]+=wv.y*xv.z; acc[1][3]+=wv.y*xv.w;
      acc[2][0]+=wv.z*xv.x; acc[2][1]+=wv.z*xv.y; acc[2][2]+=wv.z*xv.z; acc[2][3]+=wv.z*xv.w;
      acc[3][0]+=wv.w*xv.x; acc[3][1]+=wv.w*xv.y; acc[3][2]+=wv.w*xv.z; acc[3][3]+=wv.w*xv.w;
    }
  }
  #pragma unroll
  for (int i = 0; i < 4; i++){
    float bi = bsrc[r0+i];
    float4 o;
    o.x = fmaxf(acc[i][0]+bi, 0.f); o.y = fmaxf(acc[i][1]+bi, 0.f);
    o.z = fmaxf(acc[i][2]+bi, 0.f); o.w = fmaxf(acc[i][3]+bi, 0.f);
    *(float4*)(wsp + dstoff + ((size_t)b*dstC + row0 + r0 + i)*2304 + hw0 + cc0) = o;
  }
}

// ---------------- K13: all 4 upsample heads, nt stores (R9 exact) ----------------
template<int SC>
__device__ __forceinline__ void up_one(int idx, const float* __restrict__ src, float* __restrict__ dst){
  constexpr int OW = 48*SC, OH = 48*SC;
  constexpr int WQ = OW/4;
  int q = idx % WQ; int rest = idx / WQ;
  int oy = rest % OH; int pc = rest / OH;
  const float* sp = src + (size_t)pc * 2304;
  float cy = fminf(fmaxf((oy + 0.5f)*(1.0f/SC) - 0.5f, 0.f), 47.f);
  int y0 = (int)cy;
  float wy = cy - y0;
  int y1 = min(y0+1, 47);
  const float* r0 = sp + y0*48; const float* r1 = sp + y1*48;
  float outv[4];
  #pragma unroll
  for (int i = 0; i < 4; i++){
    int ox = q*4 + i;
    float cx = fminf(fmaxf((ox + 0.5f)*(1.0f/SC) - 0.5f, 0.f), 47.f);
    int x0 = (int)cx; float wx = cx - x0; int x1 = min(x0+1, 47);
    float a  = r0[x0]*(1.f-wx) + r0[x1]*wx;
    float bq = r1[x0]*(1.f-wx) + r1[x1]*wx;
    outv[i] = a*(1.f-wy) + bq*wy;
  }
  f32x4 o; o[0] = outv[0]; o[1] = outv[1]; o[2] = outv[2]; o[3] = outv[3];
  f32x4* dp = (f32x4*)(dst + (size_t)pc*OH*OW + (size_t)oy*OW + q*4);
  __builtin_nontemporal_store(o, dp);
}

__global__ __launch_bounds__(256) void k_upsample_all(const float* __restrict__ wsp, float* __restrict__ out){
  int t = blockIdx.x*256 + threadIdx.x;
  if (t < 1179648)       up_one<2>(t,           wsp + OFF_Y0, out);
  else if (t < 3538944)  up_one<4>(t - 1179648, wsp + OFF_Y1, out + 4718592);
  else if (t < 8257536)  up_one<8>(t - 3538944, wsp + OFF_Y2, out + 14155776);
  else                   up_one<16>(t - 8257536, wsp + OFF_Y3, out + 33030144);
}

// ---------------- launcher ----------------
extern "C" void kernel_launch(void* const* d_in, const int* in_sizes, int n_in,
                              void* d_out, int out_size, void* d_ws, size_t ws_size,
                              hipStream_t stream){
  const float* x     = (const float*)d_in[0];
  const float* w_gc0 = (const float*)d_in[1];
  const float* b_gc0 = (const float*)d_in[2];
  const float* w_gc1 = (const float*)d_in[3];
  const float* b_gc1 = (const float*)d_in[4];
  const float* w_gc2 = (const float*)d_in[5];
  const float* b_gc2 = (const float*)d_in[6];
  const float* w_gc3 = (const float*)d_in[7];
  const float* b_gc3 = (const float*)d_in[8];
  const float* w_q   = (const float*)d_in[9];
  const float* b_q   = (const float*)d_in[10];
  const float* w_k   = (const float*)d_in[11];
  const float* b_k   = (const float*)d_in[12];
  const float* w_v   = (const float*)d_in[13];
  const float* b_v   = (const float*)d_in[14];
  const float* gamma = (const float*)d_in[15];
  const float* w_se1 = (const float*)d_in[16];
  const float* w_se2 = (const float*)d_in[17];
  const float* w_se3 = (const float*)d_in[18];
  const float* w_se4 = (const float*)d_in[19];
  const float* w_out0 = (const float*)d_in[20];
  const float* b_out0 = (const float*)d_in[21];
  const float* w_out1 = (const float*)d_in[22];
  const float* b_out1 = (const float*)d_in[23];
  const float* w_out2 = (const float*)d_in[24];
  const float* b_out2 = (const float*)d_in[25];
  const float* w_out3 = (const float*)d_in[26];
  const float* b_out3 = (const float*)d_in[27];
  float* wsp = (float*)d_ws;
  float* out = (float*)d_out;

  k_pool      <<<1024, 256, 0, stream>>>(x, wsp);
  k_sgemm_qkv <<<144,  256, 0, stream>>>(x, w_gc3, b_gc3, w_q,b_q,w_k,b_k,w_v,b_v, wsp);
  k_attn_gcconv<<<358, 256, 0, stream>>>(wsp, gamma, w_gc0,b_gc0,w_gc1,b_gc1,w_gc2,b_gc2);
  k_gcup_se   <<<3458, 256, 0, stream>>>(wsp, w_se1,w_se2,w_se3,w_se4);
  k_outgemm   <<<dim3(72,8), 256, 0, stream>>>(w_out0,b_out0,w_out1,b_out1,w_out2,b_out2,w_out3,b_out3, wsp);
  k_upsample_all<<<105984, 256, 0, stream>>>(wsp, out);
}

// Round 12
// 215.110 us; speedup vs baseline: 1.7275x; 1.7275x over previous
//
#include <hip/hip_runtime.h>
#include <hip/hip_bf16.h>
#include <hip/hip_fp16.h>

// B=2, Cin=512, C=64, H=W=48, N=2304 spatial, 4608 total columns.
// R12 = exact R9 pipeline (217.1us best) + ONE change for bisection:
//   k_gcup + k_gap merged into k_gcup_gap (3584 blocks, same bodies).
// R11 (3 merges at once) regressed +154us with unknown mechanism; bisecting.

typedef __attribute__((ext_vector_type(8))) short short8;
typedef __attribute__((ext_vector_type(4))) float f32x4;

#define GLOAD_LDS(gsrc, ldst) \
  __builtin_amdgcn_global_load_lds((const __attribute__((address_space(1))) void*)(gsrc), \
                                   (__attribute__((address_space(3))) void*)(ldst), 16, 0, 0)

// ---------------- ws layout (float offsets) ----------------
static constexpr size_t OFF_P1 = 0;                       // [2][512]
static constexpr size_t OFF_P3 = OFF_P1 + 2*512;          // [2*9][512]
static constexpr size_t OFF_P5 = OFF_P3 + 18*512;         // [2*25][512]
static constexpr size_t OFF_G0 = OFF_P5 + 50*512;         // [2*1][64]
static constexpr size_t OFF_G1 = OFF_G0 + 2*64;           // [2*9][64]
static constexpr size_t OFF_G2 = OFF_G1 + 18*64;          // [2*25][64]
static constexpr size_t OFF_S  = OFF_G2 + 50*64;          // [2][64][2304] f32
static constexpr size_t OFF_Q  = OFF_S  + 294912;         // [2][8][2304] f32
static constexpr size_t OFF_K  = OFF_Q  + 36864;          // [2][8][2304] f32
static constexpr size_t OFF_V  = OFF_K  + 36864;          // bf16 [2][64][2304]
static constexpr size_t OFF_SA = OFF_V  + 294912;         // [2][64][2304] f32
static constexpr size_t OFF_GC = OFF_SA + 294912;         // [3][2][64][2304] f32
static constexpr size_t OFF_MEAN = OFF_GC + 3*294912;     // [2][64]
static constexpr size_t OFF_WGT  = OFF_MEAN + 512;        // [2][4][64]
static constexpr size_t OFF_Y0 = OFF_WGT + 512;           // [2][256][2304]
static constexpr size_t OFF_Y1 = OFF_Y0 + 1179648;        // [2][128][2304]
static constexpr size_t OFF_Y2 = OFF_Y1 + 589824;         // [2][64][2304]
static constexpr size_t OFF_Y3 = OFF_Y2 + 294912;         // [2][64][2304]

// ---------------- K1: adaptive pools (1,3,5) ----------------
__global__ __launch_bounds__(256) void k_pool(const float* __restrict__ x, float* __restrict__ wsp){
  __shared__ float pl[2304];
  __shared__ float red[4];
  int bc = blockIdx.x;            // b*512 + cin
  int b = bc >> 9, cin = bc & 511;
  const float* src = x + (size_t)bc * 2304;
  int t = threadIdx.x;
  float ls = 0.f;
  #pragma unroll
  for (int j = 0; j < 9; j++){ int i = t + j*256; float v = src[i]; pl[i] = v; ls += v; }
  #pragma unroll
  for (int o = 32; o; o >>= 1) ls += __shfl_xor(ls, o);
  if ((t & 63) == 0) red[t >> 6] = ls;
  __syncthreads();
  if (t == 0) wsp[OFF_P1 + (size_t)b*512 + cin] = (red[0]+red[1]+red[2]+red[3]) * (1.f/2304.f);
  if (t < 9){
    int ry = t/3, rx = t%3; float sm = 0.f;
    for (int yy = 0; yy < 16; yy++)
      for (int xx = 0; xx < 16; xx++) sm += pl[(ry*16+yy)*48 + rx*16+xx];
    wsp[OFF_P3 + ((size_t)b*9 + t)*512 + cin] = sm * (1.f/256.f);
  } else if (t < 34){
    int j = t - 9; int ry = j/5, rx = j%5;
    int hs = (ry*48)/5, he = ((ry+1)*48+4)/5, cs = (rx*48)/5, ce = ((rx+1)*48+4)/5;
    float sm = 0.f;
    for (int yy = hs; yy < he; yy++)
      for (int xx = cs; xx < ce; xx++) sm += pl[yy*48+xx];
    wsp[OFF_P5 + ((size_t)b*25 + j)*512 + cin] = sm / (float)((he-hs)*(ce-cs));
  }
}

// ---------------- K2: tiny 64x512 convs on pooled cols ----------------
__global__ __launch_bounds__(256) void k_gcconv(
    const float* __restrict__ w0, const float* __restrict__ b0,
    const float* __restrict__ w1, const float* __restrict__ b1,
    const float* __restrict__ w2, const float* __restrict__ b2,
    float* __restrict__ wsp){
  int col = blockIdx.x;          // 0..69
  const float* w; const float* bias; const float* pool; float* dst;
  if (col < 2){ w = w0; bias = b0; pool = wsp + OFF_P1 + (size_t)col*512; dst = wsp + OFF_G0 + (size_t)col*64; }
  else if (col < 20){ int c = col-2;  w = w1; bias = b1; pool = wsp + OFF_P3 + (size_t)c*512; dst = wsp + OFF_G1 + (size_t)c*64; }
  else              { int c = col-20; w = w2; bias = b2; pool = wsp + OFF_P5 + (size_t)c*512; dst = wsp + OFF_G2 + (size_t)c*64; }
  int t = threadIdx.x; int r = t >> 2, qd = t & 3;
  const float* wr = w + (size_t)r*512 + qd*128;
  const float* pr = pool + qd*128;
  float acc = 0.f;
  #pragma unroll 8
  for (int k = 0; k < 128; k += 4){
    float4 wv = *(const float4*)(wr + k); float4 pv = *(const float4*)(pr + k);
    acc += wv.x*pv.x + wv.y*pv.y + wv.z*pv.z + wv.w*pv.w;
  }
  acc += __shfl_xor(acc, 1); acc += __shfl_xor(acc, 2);
  if (qd == 0) dst[r] = fmaxf(acc + bias[r], 0.f);
}

// ---------------- K3: s = relu(Wgc3.x+b) + fused QKV, X staged via global_load_lds ----------------
__global__ __launch_bounds__(256) void k_sgemm_qkv(const float* __restrict__ x,
    const float* __restrict__ w, const float* __restrict__ bias,
    const float* __restrict__ wq, const float* __restrict__ bq,
    const float* __restrict__ wk, const float* __restrict__ bk,
    const float* __restrict__ wv, const float* __restrict__ bv,
    float* __restrict__ wsp){
  __shared__ __align__(16) float wt[64][66];     // [k][row]
  __shared__ __align__(16) float xs[64][32];     // [k][col] staged X chunk
  __shared__ __align__(16) float s_lds[64][36];  // [chan][col]
  __shared__ float wq_lds[80][64];
  __shared__ float bqkv[80];
  int cb = blockIdx.x;
  int b = cb / 72, hw0 = (cb - b*72)*32;
  int tid = threadIdx.x;
  int wv_ = tid >> 6, lane = tid & 63;
  for (int i = tid; i < 5120; i += 256){
    int row = i >> 6, k = i & 63;
    wq_lds[row][k] = (row < 8) ? wq[(size_t)row*64 + k]
                   : (row < 16) ? wk[(size_t)(row-8)*64 + k]
                                : wv[(size_t)(row-16)*64 + k];
  }
  if (tid < 80) bqkv[tid] = (tid < 8) ? bq[tid] : (tid < 16) ? bk[tid-8] : bv[tid-16];
  int sr = tid >> 2, sseg = tid & 3;
  int cc0 = (tid & 7)*4, r0 = (tid >> 3)*2;
  const float* xb = x + (size_t)b*512*2304 + hw0;
  float acc[2][4] = {};
  for (int kc = 0; kc < 512; kc += 64){
    __syncthreads();
    {
      int rr0 = wv_*16 + (lane >> 3);
      const float* g0 = xb + (size_t)(kc + rr0)*2304 + (lane & 7)*4;
      const float* g1 = xb + (size_t)(kc + rr0 + 8)*2304 + (lane & 7)*4;
      GLOAD_LDS(g0, &xs[wv_*16][0]);
      GLOAD_LDS(g1, &xs[wv_*16 + 8][0]);
    }
    #pragma unroll
    for (int i = 0; i < 16; i += 4){
      float4 v = *(const float4*)(w + (size_t)sr*512 + kc + sseg*16 + i);
      wt[sseg*16+i+0][sr]=v.x; wt[sseg*16+i+1][sr]=v.y;
      wt[sseg*16+i+2][sr]=v.z; wt[sseg*16+i+3][sr]=v.w;
    }
    __syncthreads();
    #pragma unroll 4
    for (int k = 0; k < 64; k++){
      float2 wv2 = *(const float2*)&wt[k][r0];
      float4 xv = *(const float4*)&xs[k][cc0];
      acc[0][0]+=wv2.x*xv.x; acc[0][1]+=wv2.x*xv.y; acc[0][2]+=wv2.x*xv.z; acc[0][3]+=wv2.x*xv.w;
      acc[1][0]+=wv2.y*xv.x; acc[1][1]+=wv2.y*xv.y; acc[1][2]+=wv2.y*xv.z; acc[1][3]+=wv2.y*xv.w;
    }
  }
  #pragma unroll
  for (int i = 0; i < 2; i++){
    float bi = bias[r0+i];
    float4 o;
    o.x = fmaxf(acc[i][0]+bi, 0.f); o.y = fmaxf(acc[i][1]+bi, 0.f);
    o.z = fmaxf(acc[i][2]+bi, 0.f); o.w = fmaxf(acc[i][3]+bi, 0.f);
    *(float4*)(wsp + OFF_S + ((size_t)b*64 + r0+i)*2304 + hw0 + cc0) = o;
    *(float4*)&s_lds[r0+i][cc0] = o;
  }
  __syncthreads();
  int col = tid & 31, rgrp = tid >> 5;
  float a2[10];
  #pragma unroll
  for (int i = 0; i < 10; i++) a2[i] = bqkv[rgrp*10 + i];
  for (int k = 0; k < 64; k++){
    float sv = s_lds[k][col];
    #pragma unroll
    for (int i = 0; i < 10; i++) a2[i] += wq_lds[rgrp*10 + i][k]*sv;
  }
  __hip_bfloat16* Vb = reinterpret_cast<__hip_bfloat16*>(wsp + OFF_V);
  int hw = hw0 + col;
  #pragma unroll
  for (int i = 0; i < 10; i++){
    int r = rgrp*10 + i;
    if (r < 8)       wsp[OFF_Q + (size_t)b*18432 + (size_t)r*2304 + hw] = a2[i];
    else if (r < 16) wsp[OFF_K + (size_t)b*18432 + (size_t)(r-8)*2304 + hw] = a2[i];
    else             Vb[(size_t)b*147456 + (size_t)(r-16)*2304 + hw] = __float2bfloat16(a2[i]);
  }
}

// ---------------- K4: flash attention ----------------
__global__ __launch_bounds__(256) void k_attn(float* __restrict__ wsp, const float* __restrict__ gamma){
  int mb = blockIdx.x * 16;
  int b  = blockIdx.y;
  int t = threadIdx.x;
  int w = t >> 6, lane = t & 63;
  int arow = lane & 15, kg = lane >> 4;
  __shared__ float qs[16][8];
  __shared__ __align__(16) unsigned short plds[16][2312];
  __shared__ float redM[4][16], redS[4][16];
  __shared__ float tile[16][68];
  const float* Qp = wsp + OFF_Q + (size_t)b*18432;
  const float* Kp = wsp + OFF_K + (size_t)b*18432;
  if (t < 128) qs[t>>3][t&7] = Qp[(size_t)(t&7)*2304 + mb + (t>>3)];
  __syncthreads();
  float k8[9][8];
  #pragma unroll
  for (int j = 0; j < 9; j++){
    int n = j*256 + t;
    #pragma unroll
    for (int c = 0; c < 8; c++) k8[j][c] = Kp[(size_t)c*2304 + n];
  }
  float mx[16], ssum[16];
  #pragma unroll
  for (int m = 0; m < 16; m++){
    float q0=qs[m][0], q1=qs[m][1], q2=qs[m][2], q3=qs[m][3];
    float q4=qs[m][4], q5=qs[m][5], q6=qs[m][6], q7=qs[m][7];
    float lmx = -1e30f, ls = 0.f;
    #pragma unroll
    for (int j = 0; j < 9; j++){
      float l = q0*k8[j][0]+q1*k8[j][1]+q2*k8[j][2]+q3*k8[j][3]
              + q4*k8[j][4]+q5*k8[j][5]+q6*k8[j][6]+q7*k8[j][7];
      __half hv = __float2half(l);
      plds[m][j*256 + t] = __half_as_ushort(hv);
      float mo = lmx;
      lmx = fmaxf(lmx, l);
      ls = ls*__expf(mo - lmx) + __expf(l - lmx);
    }
    mx[m] = lmx; ssum[m] = ls;
  }
  #pragma unroll
  for (int m = 0; m < 16; m++){
    float M = mx[m], S = ssum[m];
    #pragma unroll
    for (int off = 32; off; off >>= 1){
      float oM = __shfl_xor(M, off), oS = __shfl_xor(S, off);
      float nM = fmaxf(M, oM);
      S = S*__expf(M - nM) + oS*__expf(oM - nM);
      M = nM;
    }
    if (lane == 0){ redM[w][m] = M; redS[w][m] = S; }
  }
  __syncthreads();
  float Mf[16], invS[16];
  #pragma unroll
  for (int m = 0; m < 16; m++){
    float M0 = redM[0][m], M1 = redM[1][m], M2 = redM[2][m], M3 = redM[3][m];
    float M = fmaxf(fmaxf(M0, M1), fmaxf(M2, M3));
    float S = redS[0][m]*__expf(M0-M) + redS[1][m]*__expf(M1-M)
            + redS[2][m]*__expf(M2-M) + redS[3][m]*__expf(M3-M);
    Mf[m] = M; invS[m] = 1.f/S;
  }
  const short* Vb = (const short*)(wsp + OFF_V) + (size_t)b*147456 + (size_t)(w*16 + arow)*2304;
  f32x4 acc = {0.f, 0.f, 0.f, 0.f};
  for (int j = 0; j < 9; j++){
    int n = j*256 + t;
    #pragma unroll
    for (int m = 0; m < 16; m++){
      float l = __half2float(__ushort_as_half(plds[m][n]));
      float p = __expf(l - Mf[m]) * invS[m];
      __hip_bfloat16 pb = __float2bfloat16(p);
      plds[m][n] = *(unsigned short*)&pb;
    }
    __syncthreads();
    #pragma unroll
    for (int ks = 0; ks < 8; ks++){
      int nb = j*256 + ks*32 + kg*8;
      short8 a  = *(const short8*)&plds[arow][nb];
      short8 bv = *(const short8*)(Vb + nb);
      acc = __builtin_amdgcn_mfma_f32_16x16x32_bf16(a, bv, acc, 0, 0, 0);
    }
  }
  #pragma unroll
  for (int r = 0; r < 4; r++) tile[kg*4 + r][w*16 + arow] = acc[r];
  __syncthreads();
  int c = t >> 2, mq = t & 3;
  float g = gamma[0];
  const float* Sp = wsp + OFF_S + (size_t)b*147456 + (size_t)c*2304 + mb + mq*4;
  float4 s4 = *(const float4*)Sp;
  float4 o;
  o.x = g*tile[mq*4+0][c] + s4.x;
  o.y = g*tile[mq*4+1][c] + s4.y;
  o.z = g*tile[mq*4+2][c] + s4.z;
  o.w = g*tile[mq*4+3][c] + s4.w;
  *(float4*)(wsp + OFF_SA + (size_t)b*147456 + (size_t)c*2304 + mb + mq*4) = o;
}

// ---------------- K8+K9 merged: gcup (0..3455) + gap (3456..3583) ----------------
__device__ void gcup_body(int u, float* __restrict__ wsp){
  int px = (u % 9)*256 + threadIdx.x;      // 0..2303
  int pb = u / 9;                          // t*128 + b*64 + c
  int c = pb & 63, b = (pb >> 6) & 1, t = pb >> 7;
  int oy = px / 48, ox = px - oy*48;
  int ps; const float* g;
  if (t == 0){ ps = 1; g = wsp + OFF_G0 + (size_t)b*64; }
  else if (t == 1){ ps = 3; g = wsp + OFF_G1 + (size_t)b*9*64; }
  else { ps = 5; g = wsp + OFF_G2 + (size_t)b*25*64; }
  float scale = (ps - 1) / 47.f;
  float cy = oy*scale, cx = ox*scale;
  int y0 = (int)cy, x0 = (int)cx;
  float wy = cy - y0, wx = cx - x0;
  int y1 = min(y0+1, ps-1), x1 = min(x0+1, ps-1);
  float a  = g[(y0*ps+x0)*64 + c], bq = g[(y0*ps+x1)*64 + c];
  float cc = g[(y1*ps+x0)*64 + c], d  = g[(y1*ps+x1)*64 + c];
  float v = (a*(1.f-wx) + bq*wx)*(1.f-wy) + (cc*(1.f-wx) + d*wx)*wy;
  wsp[OFF_GC + (((size_t)t*2 + b)*64 + c)*2304 + px] = v;
}

__device__ void gap_body(int blk, float* __restrict__ wsp){
  __shared__ float red[4];
  int c = blk & 63, b = blk >> 6;          // 128 blocks
  const float* src = wsp + OFF_SA + ((size_t)b*64 + c)*2304;
  float s = 0.f;
  for (int i = threadIdx.x; i < 2304; i += 256) s += src[i];
  #pragma unroll
  for (int o = 32; o; o >>= 1) s += __shfl_xor(s, o);
  if ((threadIdx.x & 63) == 0) red[threadIdx.x >> 6] = s;
  __syncthreads();
  if (threadIdx.x == 0)
    wsp[OFF_MEAN + (size_t)b*64 + c] = (red[0]+red[1]+red[2]+red[3]) * (1.f/2304.f);
}

__global__ __launch_bounds__(256) void k_gcup_gap(float* __restrict__ wsp){
  int bx = blockIdx.x;
  if (bx < 3456) gcup_body(bx, wsp);
  else           gap_body(bx - 3456, wsp);
}

// ---------------- K10: SE (gc means analytic from G) ----------------
__global__ __launch_bounds__(256) void k_se(
    const float* __restrict__ w_se1, const float* __restrict__ w_se2,
    const float* __restrict__ w_se3, const float* __restrict__ w_se4,
    float* __restrict__ wsp){
  int b = blockIdx.x; int tid = threadIdx.x;
  int g = tid >> 6, c = tid & 63;
  __shared__ float mean_lds[4][64];
  float mv;
  if (g == 0){
    mv = wsp[OFF_MEAN + (size_t)b*64 + c];
  } else if (g == 3){
    mv = wsp[OFF_G0 + (size_t)b*64 + c];
  } else if (g == 2){
    float w3[3] = {0.f,0.f,0.f};
    for (int o = 0; o < 48; o++){
      float cc = o*(2.f/47.f); int i0 = (int)cc; float f = cc - i0;
      int i1 = min(i0+1, 2);
      w3[i0] += 1.f - f; w3[i1] += f;
    }
    float s = 0.f;
    for (int sy = 0; sy < 3; sy++)
      for (int sx = 0; sx < 3; sx++)
        s += w3[sy]*w3[sx]*wsp[OFF_G1 + ((size_t)b*9 + sy*3 + sx)*64 + c];
    mv = s * (1.f/(48.f*48.f));
  } else {
    float w5[5] = {0.f,0.f,0.f,0.f,0.f};
    for (int o = 0; o < 48; o++){
      float cc = o*(4.f/47.f); int i0 = (int)cc; float f = cc - i0;
      int i1 = min(i0+1, 4);
      w5[i0] += 1.f - f; w5[i1] += f;
    }
    float s = 0.f;
    for (int sy = 0; sy < 5; sy++)
      for (int sx = 0; sx < 5; sx++)
        s += w5[sy]*w5[sx]*wsp[OFF_G2 + ((size_t)b*25 + sy*5 + sx)*64 + c];
    mv = s * (1.f/(48.f*48.f));
  }
  mean_lds[g][c] = mv;
  __syncthreads();
  const float* w = (g == 0) ? w_se1 : (g == 1) ? w_se2 : (g == 2) ? w_se3 : w_se4;
  float acc = 0.f;
  for (int j = 0; j < 64; j++) acc += w[(size_t)c*64 + j]*mean_lds[g][j];
  float sg = 1.f / (1.f + __expf(-acc));
  __shared__ float sh[4][64];
  sh[g][c] = sg;
  __syncthreads();
  float a0 = sh[0][c], a1 = sh[1][c], a2 = sh[2][c], a3 = sh[3][c];
  float mxv = fmaxf(fmaxf(a0, a1), fmaxf(a2, a3));
  float e = __expf(sg - mxv);
  float sum = __expf(a0-mxv) + __expf(a1-mxv) + __expf(a2-mxv) + __expf(a3-mxv);
  wsp[OFF_WGT + ((size_t)b*4 + g)*64 + c] = e / sum;
}

// ---------------- K12: out-head GEMMs, wgt folded, X staged via global_load_lds ----------------
__global__ __launch_bounds__(256) void k_outgemm(
    const float* __restrict__ w0, const float* __restrict__ b0,
    const float* __restrict__ w1, const float* __restrict__ b1,
    const float* __restrict__ w2, const float* __restrict__ b2,
    const float* __restrict__ w3, const float* __restrict__ b3,
    float* __restrict__ wsp){
  __shared__ __align__(16) float wt[64][68];
  __shared__ __align__(16) float xsh[64][64];   // staged activation chunk (16 KB, linear)
  __shared__ float wg[256];
  int cb = blockIdx.x, rb = blockIdx.y;
  int b = cb / 36, hw0 = (cb - b*36)*64;
  const float* wsrc; const float* bsrc; size_t dstoff; int dstC; int row0;
  if (rb < 4){ wsrc = w0 + (size_t)rb*64*256; bsrc = b0 + rb*64; dstoff = OFF_Y0; dstC = 256; row0 = rb*64; }
  else if (rb < 6){ wsrc = w1 + (size_t)(rb-4)*64*256; bsrc = b1 + (rb-4)*64; dstoff = OFF_Y1; dstC = 128; row0 = (rb-4)*64; }
  else if (rb == 6){ wsrc = w2; bsrc = b2; dstoff = OFF_Y2; dstC = 64; row0 = 0; }
  else { wsrc = w3; bsrc = b3; dstoff = OFF_Y3; dstC = 64; row0 = 0; }
  int tid = threadIdx.x;
  int wv_ = tid >> 6, lane = tid & 63;
  wg[tid] = wsp[OFF_WGT + (size_t)b*256 + tid];
  int sr = tid >> 2, sseg = tid & 3;
  int cc0 = (tid & 15)*4, r0 = (tid >> 4)*4;
  float acc[4][4] = {};
  for (int kc = 0; kc < 256; kc += 64){
    __syncthreads();
    {
      int gidx = kc >> 6;
      size_t srcbase = (gidx < 3) ? OFF_GC + ((size_t)(gidx*2 + b))*147456
                                  : OFF_SA + (size_t)b*147456;
      const float* gb = wsp + srcbase + hw0 + (lane & 15)*4;
      int rr = wv_*16 + (lane >> 4);
      #pragma unroll
      for (int i = 0; i < 4; i++)
        GLOAD_LDS(gb + (size_t)(rr + i*4)*2304, &xsh[wv_*16 + i*4][0]);
    }
    #pragma unroll
    for (int i = 0; i < 16; i += 4){
      float4 v = *(const float4*)(wsrc + (size_t)sr*256 + kc + sseg*16 + i);
      int kl = sseg*16 + i;
      wt[kl+0][sr]=v.x*wg[kc+kl+0]; wt[kl+1][sr]=v.y*wg[kc+kl+1];
      wt[kl+2][sr]=v.z*wg[kc+kl+2]; wt[kl+3][sr]=v.w*wg[kc+kl+3];
    }
    __syncthreads();
    #pragma unroll 4
    for (int k = 0; k < 64; k++){
      float4 wv = *(const float4*)&wt[k][r0];
      float4 xv = *(const float4*)&xsh[k][cc0];
      acc[0][0]+=wv.x*xv.x; acc[0][1]+=wv.x*xv.y; acc[0][2]+=wv.x*xv.z; acc[0][3]+=wv.x*xv.w;
      acc[1][0]+=wv.y*xv.x; acc[1][1]+=wv.y*xv.y; acc[1][2]+=wv.y*xv.z; acc[1][3]+=wv.y*xv.w;
      acc[2][0]+=wv.z*xv.x; acc[2][1]+=wv.z*xv.y; acc[2][2]+=wv.z*xv.z; acc[2][3]+=wv.z*xv.w;
      acc[3][0]+=wv.w*xv.x; acc[3][1]+=wv.w*xv.y; acc[3][2]+=wv.w*xv.z; acc[3][3]+=wv.w*xv.w;
    }
  }
  #pragma unroll
  for (int i = 0; i < 4; i++){
    float bi = bsrc[r0+i];
    float4 o;
    o.x = fmaxf(acc[i][0]+bi, 0.f); o.y = fmaxf(acc[i][1]+bi, 0.f);
    o.z = fmaxf(acc[i][2]+bi, 0.f); o.w = fmaxf(acc[i][3]+bi, 0.f);
    *(float4*)(wsp + dstoff + ((size_t)b*dstC + row0 + r0 + i)*2304 + hw0 + cc0) = o;
  }
}

// ---------------- K13: all 4 upsample heads, NON-TEMPORAL output stores ----------------
template<int SC>
__device__ __forceinline__ void up_one(int idx, const float* __restrict__ src, float* __restrict__ dst){
  constexpr int OW = 48*SC, OH = 48*SC;
  constexpr int WQ = OW/4;
  int q = idx % WQ; int rest = idx / WQ;
  int oy = rest % OH; int pc = rest / OH;
  const float* sp = src + (size_t)pc * 2304;
  float cy = fminf(fmaxf((oy + 0.5f)*(1.0f/SC) - 0.5f, 0.f), 47.f);
  int y0 = (int)cy;
  float wy = cy - y0;
  int y1 = min(y0+1, 47);
  const float* r0 = sp + y0*48; const float* r1 = sp + y1*48;
  float outv[4];
  #pragma unroll
  for (int i = 0; i < 4; i++){
    int ox = q*4 + i;
    float cx = fminf(fmaxf((ox + 0.5f)*(1.0f/SC) - 0.5f, 0.f), 47.f);
    int x0 = (int)cx; float wx = cx - x0; int x1 = min(x0+1, 47);
    float a  = r0[x0]*(1.f-wx) + r0[x1]*wx;
    float bq = r1[x0]*(1.f-wx) + r1[x1]*wx;
    outv[i] = a*(1.f-wy) + bq*wy;
  }
  f32x4 o; o[0] = outv[0]; o[1] = outv[1]; o[2] = outv[2]; o[3] = outv[3];
  f32x4* dp = (f32x4*)(dst + (size_t)pc*OH*OW + (size_t)oy*OW + q*4);
  __builtin_nontemporal_store(o, dp);   // bypass L2 line allocation
}

__global__ __launch_bounds__(256) void k_upsample_all(const float* __restrict__ wsp, float* __restrict__ out){
  int t = blockIdx.x*256 + threadIdx.x;
  if (t < 1179648)       up_one<2>(t,           wsp + OFF_Y0, out);
  else if (t < 3538944)  up_one<4>(t - 1179648, wsp + OFF_Y1, out + 4718592);
  else if (t < 8257536)  up_one<8>(t - 3538944, wsp + OFF_Y2, out + 14155776);
  else                   up_one<16>(t - 8257536, wsp + OFF_Y3, out + 33030144);
}

// ---------------- launcher ----------------
extern "C" void kernel_launch(void* const* d_in, const int* in_sizes, int n_in,
                              void* d_out, int out_size, void* d_ws, size_t ws_size,
                              hipStream_t stream){
  const float* x     = (const float*)d_in[0];
  const float* w_gc0 = (const float*)d_in[1];
  const float* b_gc0 = (const float*)d_in[2];
  const float* w_gc1 = (const float*)d_in[3];
  const float* b_gc1 = (const float*)d_in[4];
  const float* w_gc2 = (const float*)d_in[5];
  const float* b_gc2 = (const float*)d_in[6];
  const float* w_gc3 = (const float*)d_in[7];
  const float* b_gc3 = (const float*)d_in[8];
  const float* w_q   = (const float*)d_in[9];
  const float* b_q   = (const float*)d_in[10];
  const float* w_k   = (const float*)d_in[11];
  const float* b_k   = (const float*)d_in[12];
  const float* w_v   = (const float*)d_in[13];
  const float* b_v   = (const float*)d_in[14];
  const float* gamma = (const float*)d_in[15];
  const float* w_se1 = (const float*)d_in[16];
  const float* w_se2 = (const float*)d_in[17];
  const float* w_se3 = (const float*)d_in[18];
  const float* w_se4 = (const float*)d_in[19];
  const float* w_out0 = (const float*)d_in[20];
  const float* b_out0 = (const float*)d_in[21];
  const float* w_out1 = (const float*)d_in[22];
  const float* b_out1 = (const float*)d_in[23];
  const float* w_out2 = (const float*)d_in[24];
  const float* b_out2 = (const float*)d_in[25];
  const float* w_out3 = (const float*)d_in[26];
  const float* b_out3 = (const float*)d_in[27];
  float* wsp = (float*)d_ws;
  float* out = (float*)d_out;

  k_pool     <<<1024, 256, 0, stream>>>(x, wsp);
  k_gcconv   <<<70,   256, 0, stream>>>(w_gc0,b_gc0,w_gc1,b_gc1,w_gc2,b_gc2, wsp);
  k_sgemm_qkv<<<144,  256, 0, stream>>>(x, w_gc3, b_gc3, w_q,b_q,w_k,b_k,w_v,b_v, wsp);
  k_attn     <<<dim3(144,2), 256, 0, stream>>>(wsp, gamma);
  k_gcup_gap <<<3584, 256, 0, stream>>>(wsp);
  k_se       <<<2,    256, 0, stream>>>(w_se1,w_se2,w_se3,w_se4, wsp);
  k_outgemm  <<<dim3(72,8), 256, 0, stream>>>(w_out0,b_out0,w_out1,b_out1,w_out2,b_out2,w_out3,b_out3, wsp);
  k_upsample_all<<<105984, 256, 0, stream>>>(wsp, out);
}

// Round 13
// 202.005 us; speedup vs baseline: 1.8396x; 1.0649x over previous
//
#include <hip/hip_runtime.h>
#include <hip/hip_bf16.h>
#include <hip/hip_fp16.h>

// B=2, Cin=512, C=64, H=W=48, N=2304 spatial, 4608 total columns.
// R13 = exact R12 pipeline (215.1us best) + ONE change:
//   upsample heads SC>=4 specialized to a 6-load source window per 4-px group
//   (16 -> 6 gather loads/thread; tests the vmem-issue-bound hypothesis for
//   the ~125us upsample vs its ~70us traffic floor).
// R11 postmortem (recorded): folding SA-mean into 2-block k_se serialized
// 589KB of latency-bound reads on 8 waves => +150us. Never de-parallelize
// a reduction below ~1 block/CU.

typedef __attribute__((ext_vector_type(8))) short short8;
typedef __attribute__((ext_vector_type(4))) float f32x4;

#define GLOAD_LDS(gsrc, ldst) \
  __builtin_amdgcn_global_load_lds((const __attribute__((address_space(1))) void*)(gsrc), \
                                   (__attribute__((address_space(3))) void*)(ldst), 16, 0, 0)

// ---------------- ws layout (float offsets) ----------------
static constexpr size_t OFF_P1 = 0;                       // [2][512]
static constexpr size_t OFF_P3 = OFF_P1 + 2*512;          // [2*9][512]
static constexpr size_t OFF_P5 = OFF_P3 + 18*512;         // [2*25][512]
static constexpr size_t OFF_G0 = OFF_P5 + 50*512;         // [2*1][64]
static constexpr size_t OFF_G1 = OFF_G0 + 2*64;           // [2*9][64]
static constexpr size_t OFF_G2 = OFF_G1 + 18*64;          // [2*25][64]
static constexpr size_t OFF_S  = OFF_G2 + 50*64;          // [2][64][2304] f32
static constexpr size_t OFF_Q  = OFF_S  + 294912;         // [2][8][2304] f32
static constexpr size_t OFF_K  = OFF_Q  + 36864;          // [2][8][2304] f32
static constexpr size_t OFF_V  = OFF_K  + 36864;          // bf16 [2][64][2304]
static constexpr size_t OFF_SA = OFF_V  + 294912;         // [2][64][2304] f32
static constexpr size_t OFF_GC = OFF_SA + 294912;         // [3][2][64][2304] f32
static constexpr size_t OFF_MEAN = OFF_GC + 3*294912;     // [2][64]
static constexpr size_t OFF_WGT  = OFF_MEAN + 512;        // [2][4][64]
static constexpr size_t OFF_Y0 = OFF_WGT + 512;           // [2][256][2304]
static constexpr size_t OFF_Y1 = OFF_Y0 + 1179648;        // [2][128][2304]
static constexpr size_t OFF_Y2 = OFF_Y1 + 589824;         // [2][64][2304]
static constexpr size_t OFF_Y3 = OFF_Y2 + 294912;         // [2][64][2304]

// ---------------- K1: adaptive pools (1,3,5) ----------------
__global__ __launch_bounds__(256) void k_pool(const float* __restrict__ x, float* __restrict__ wsp){
  __shared__ float pl[2304];
  __shared__ float red[4];
  int bc = blockIdx.x;            // b*512 + cin
  int b = bc >> 9, cin = bc & 511;
  const float* src = x + (size_t)bc * 2304;
  int t = threadIdx.x;
  float ls = 0.f;
  #pragma unroll
  for (int j = 0; j < 9; j++){ int i = t + j*256; float v = src[i]; pl[i] = v; ls += v; }
  #pragma unroll
  for (int o = 32; o; o >>= 1) ls += __shfl_xor(ls, o);
  if ((t & 63) == 0) red[t >> 6] = ls;
  __syncthreads();
  if (t == 0) wsp[OFF_P1 + (size_t)b*512 + cin] = (red[0]+red[1]+red[2]+red[3]) * (1.f/2304.f);
  if (t < 9){
    int ry = t/3, rx = t%3; float sm = 0.f;
    for (int yy = 0; yy < 16; yy++)
      for (int xx = 0; xx < 16; xx++) sm += pl[(ry*16+yy)*48 + rx*16+xx];
    wsp[OFF_P3 + ((size_t)b*9 + t)*512 + cin] = sm * (1.f/256.f);
  } else if (t < 34){
    int j = t - 9; int ry = j/5, rx = j%5;
    int hs = (ry*48)/5, he = ((ry+1)*48+4)/5, cs = (rx*48)/5, ce = ((rx+1)*48+4)/5;
    float sm = 0.f;
    for (int yy = hs; yy < he; yy++)
      for (int xx = cs; xx < ce; xx++) sm += pl[yy*48+xx];
    wsp[OFF_P5 + ((size_t)b*25 + j)*512 + cin] = sm / (float)((he-hs)*(ce-cs));
  }
}

// ---------------- K2: tiny 64x512 convs on pooled cols ----------------
__global__ __launch_bounds__(256) void k_gcconv(
    const float* __restrict__ w0, const float* __restrict__ b0,
    const float* __restrict__ w1, const float* __restrict__ b1,
    const float* __restrict__ w2, const float* __restrict__ b2,
    float* __restrict__ wsp){
  int col = blockIdx.x;          // 0..69
  const float* w; const float* bias; const float* pool; float* dst;
  if (col < 2){ w = w0; bias = b0; pool = wsp + OFF_P1 + (size_t)col*512; dst = wsp + OFF_G0 + (size_t)col*64; }
  else if (col < 20){ int c = col-2;  w = w1; bias = b1; pool = wsp + OFF_P3 + (size_t)c*512; dst = wsp + OFF_G1 + (size_t)c*64; }
  else              { int c = col-20; w = w2; bias = b2; pool = wsp + OFF_P5 + (size_t)c*512; dst = wsp + OFF_G2 + (size_t)c*64; }
  int t = threadIdx.x; int r = t >> 2, qd = t & 3;
  const float* wr = w + (size_t)r*512 + qd*128;
  const float* pr = pool + qd*128;
  float acc = 0.f;
  #pragma unroll 8
  for (int k = 0; k < 128; k += 4){
    float4 wv = *(const float4*)(wr + k); float4 pv = *(const float4*)(pr + k);
    acc += wv.x*pv.x + wv.y*pv.y + wv.z*pv.z + wv.w*pv.w;
  }
  acc += __shfl_xor(acc, 1); acc += __shfl_xor(acc, 2);
  if (qd == 0) dst[r] = fmaxf(acc + bias[r], 0.f);
}

// ---------------- K3: s = relu(Wgc3.x+b) + fused QKV, X staged via global_load_lds ----------------
__global__ __launch_bounds__(256) void k_sgemm_qkv(const float* __restrict__ x,
    const float* __restrict__ w, const float* __restrict__ bias,
    const float* __restrict__ wq, const float* __restrict__ bq,
    const float* __restrict__ wk, const float* __restrict__ bk,
    const float* __restrict__ wv, const float* __restrict__ bv,
    float* __restrict__ wsp){
  __shared__ __align__(16) float wt[64][66];     // [k][row]
  __shared__ __align__(16) float xs[64][32];     // [k][col] staged X chunk
  __shared__ __align__(16) float s_lds[64][36];  // [chan][col]
  __shared__ float wq_lds[80][64];
  __shared__ float bqkv[80];
  int cb = blockIdx.x;
  int b = cb / 72, hw0 = (cb - b*72)*32;
  int tid = threadIdx.x;
  int wv_ = tid >> 6, lane = tid & 63;
  for (int i = tid; i < 5120; i += 256){
    int row = i >> 6, k = i & 63;
    wq_lds[row][k] = (row < 8) ? wq[(size_t)row*64 + k]
                   : (row < 16) ? wk[(size_t)(row-8)*64 + k]
                                : wv[(size_t)(row-16)*64 + k];
  }
  if (tid < 80) bqkv[tid] = (tid < 8) ? bq[tid] : (tid < 16) ? bk[tid-8] : bv[tid-16];
  int sr = tid >> 2, sseg = tid & 3;
  int cc0 = (tid & 7)*4, r0 = (tid >> 3)*2;
  const float* xb = x + (size_t)b*512*2304 + hw0;
  float acc[2][4] = {};
  for (int kc = 0; kc < 512; kc += 64){
    __syncthreads();
    {
      int rr0 = wv_*16 + (lane >> 3);
      const float* g0 = xb + (size_t)(kc + rr0)*2304 + (lane & 7)*4;
      const float* g1 = xb + (size_t)(kc + rr0 + 8)*2304 + (lane & 7)*4;
      GLOAD_LDS(g0, &xs[wv_*16][0]);
      GLOAD_LDS(g1, &xs[wv_*16 + 8][0]);
    }
    #pragma unroll
    for (int i = 0; i < 16; i += 4){
      float4 v = *(const float4*)(w + (size_t)sr*512 + kc + sseg*16 + i);
      wt[sseg*16+i+0][sr]=v.x; wt[sseg*16+i+1][sr]=v.y;
      wt[sseg*16+i+2][sr]=v.z; wt[sseg*16+i+3][sr]=v.w;
    }
    __syncthreads();
    #pragma unroll 4
    for (int k = 0; k < 64; k++){
      float2 wv2 = *(const float2*)&wt[k][r0];
      float4 xv = *(const float4*)&xs[k][cc0];
      acc[0][0]+=wv2.x*xv.x; acc[0][1]+=wv2.x*xv.y; acc[0][2]+=wv2.x*xv.z; acc[0][3]+=wv2.x*xv.w;
      acc[1][0]+=wv2.y*xv.x; acc[1][1]+=wv2.y*xv.y; acc[1][2]+=wv2.y*xv.z; acc[1][3]+=wv2.y*xv.w;
    }
  }
  #pragma unroll
  for (int i = 0; i < 2; i++){
    float bi = bias[r0+i];
    float4 o;
    o.x = fmaxf(acc[i][0]+bi, 0.f); o.y = fmaxf(acc[i][1]+bi, 0.f);
    o.z = fmaxf(acc[i][2]+bi, 0.f); o.w = fmaxf(acc[i][3]+bi, 0.f);
    *(float4*)(wsp + OFF_S + ((size_t)b*64 + r0+i)*2304 + hw0 + cc0) = o;
    *(float4*)&s_lds[r0+i][cc0] = o;
  }
  __syncthreads();
  int col = tid & 31, rgrp = tid >> 5;
  float a2[10];
  #pragma unroll
  for (int i = 0; i < 10; i++) a2[i] = bqkv[rgrp*10 + i];
  for (int k = 0; k < 64; k++){
    float sv = s_lds[k][col];
    #pragma unroll
    for (int i = 0; i < 10; i++) a2[i] += wq_lds[rgrp*10 + i][k]*sv;
  }
  __hip_bfloat16* Vb = reinterpret_cast<__hip_bfloat16*>(wsp + OFF_V);
  int hw = hw0 + col;
  #pragma unroll
  for (int i = 0; i < 10; i++){
    int r = rgrp*10 + i;
    if (r < 8)       wsp[OFF_Q + (size_t)b*18432 + (size_t)r*2304 + hw] = a2[i];
    else if (r < 16) wsp[OFF_K + (size_t)b*18432 + (size_t)(r-8)*2304 + hw] = a2[i];
    else             Vb[(size_t)b*147456 + (size_t)(r-16)*2304 + hw] = __float2bfloat16(a2[i]);
  }
}

// ---------------- K4: flash attention ----------------
__global__ __launch_bounds__(256) void k_attn(float* __restrict__ wsp, const float* __restrict__ gamma){
  int mb = blockIdx.x * 16;
  int b  = blockIdx.y;
  int t = threadIdx.x;
  int w = t >> 6, lane = t & 63;
  int arow = lane & 15, kg = lane >> 4;
  __shared__ float qs[16][8];
  __shared__ __align__(16) unsigned short plds[16][2312];
  __shared__ float redM[4][16], redS[4][16];
  __shared__ float tile[16][68];
  const float* Qp = wsp + OFF_Q + (size_t)b*18432;
  const float* Kp = wsp + OFF_K + (size_t)b*18432;
  if (t < 128) qs[t>>3][t&7] = Qp[(size_t)(t&7)*2304 + mb + (t>>3)];
  __syncthreads();
  float k8[9][8];
  #pragma unroll
  for (int j = 0; j < 9; j++){
    int n = j*256 + t;
    #pragma unroll
    for (int c = 0; c < 8; c++) k8[j][c] = Kp[(size_t)c*2304 + n];
  }
  float mx[16], ssum[16];
  #pragma unroll
  for (int m = 0; m < 16; m++){
    float q0=qs[m][0], q1=qs[m][1], q2=qs[m][2], q3=qs[m][3];
    float q4=qs[m][4], q5=qs[m][5], q6=qs[m][6], q7=qs[m][7];
    float lmx = -1e30f, ls = 0.f;
    #pragma unroll
    for (int j = 0; j < 9; j++){
      float l = q0*k8[j][0]+q1*k8[j][1]+q2*k8[j][2]+q3*k8[j][3]
              + q4*k8[j][4]+q5*k8[j][5]+q6*k8[j][6]+q7*k8[j][7];
      __half hv = __float2half(l);
      plds[m][j*256 + t] = __half_as_ushort(hv);
      float mo = lmx;
      lmx = fmaxf(lmx, l);
      ls = ls*__expf(mo - lmx) + __expf(l - lmx);
    }
    mx[m] = lmx; ssum[m] = ls;
  }
  #pragma unroll
  for (int m = 0; m < 16; m++){
    float M = mx[m], S = ssum[m];
    #pragma unroll
    for (int off = 32; off; off >>= 1){
      float oM = __shfl_xor(M, off), oS = __shfl_xor(S, off);
      float nM = fmaxf(M, oM);
      S = S*__expf(M - nM) + oS*__expf(oM - nM);
      M = nM;
    }
    if (lane == 0){ redM[w][m] = M; redS[w][m] = S; }
  }
  __syncthreads();
  float Mf[16], invS[16];
  #pragma unroll
  for (int m = 0; m < 16; m++){
    float M0 = redM[0][m], M1 = redM[1][m], M2 = redM[2][m], M3 = redM[3][m];
    float M = fmaxf(fmaxf(M0, M1), fmaxf(M2, M3));
    float S = redS[0][m]*__expf(M0-M) + redS[1][m]*__expf(M1-M)
            + redS[2][m]*__expf(M2-M) + redS[3][m]*__expf(M3-M);
    Mf[m] = M; invS[m] = 1.f/S;
  }
  const short* Vb = (const short*)(wsp + OFF_V) + (size_t)b*147456 + (size_t)(w*16 + arow)*2304;
  f32x4 acc = {0.f, 0.f, 0.f, 0.f};
  for (int j = 0; j < 9; j++){
    int n = j*256 + t;
    #pragma unroll
    for (int m = 0; m < 16; m++){
      float l = __half2float(__ushort_as_half(plds[m][n]));
      float p = __expf(l - Mf[m]) * invS[m];
      __hip_bfloat16 pb = __float2bfloat16(p);
      plds[m][n] = *(unsigned short*)&pb;
    }
    __syncthreads();
    #pragma unroll
    for (int ks = 0; ks < 8; ks++){
      int nb = j*256 + ks*32 + kg*8;
      short8 a  = *(const short8*)&plds[arow][nb];
      short8 bv = *(const short8*)(Vb + nb);
      acc = __builtin_amdgcn_mfma_f32_16x16x32_bf16(a, bv, acc, 0, 0, 0);
    }
  }
  #pragma unroll
  for (int r = 0; r < 4; r++) tile[kg*4 + r][w*16 + arow] = acc[r];
  __syncthreads();
  int c = t >> 2, mq = t & 3;
  float g = gamma[0];
  const float* Sp = wsp + OFF_S + (size_t)b*147456 + (size_t)c*2304 + mb + mq*4;
  float4 s4 = *(const float4*)Sp;
  float4 o;
  o.x = g*tile[mq*4+0][c] + s4.x;
  o.y = g*tile[mq*4+1][c] + s4.y;
  o.z = g*tile[mq*4+2][c] + s4.z;
  o.w = g*tile[mq*4+3][c] + s4.w;
  *(float4*)(wsp + OFF_SA + (size_t)b*147456 + (size_t)c*2304 + mb + mq*4) = o;
}

// ---------------- K8+K9 merged: gcup (0..3455) + gap (3456..3583) ----------------
__device__ void gcup_body(int u, float* __restrict__ wsp){
  int px = (u % 9)*256 + threadIdx.x;      // 0..2303
  int pb = u / 9;                          // t*128 + b*64 + c
  int c = pb & 63, b = (pb >> 6) & 1, t = pb >> 7;
  int oy = px / 48, ox = px - oy*48;
  int ps; const float* g;
  if (t == 0){ ps = 1; g = wsp + OFF_G0 + (size_t)b*64; }
  else if (t == 1){ ps = 3; g = wsp + OFF_G1 + (size_t)b*9*64; }
  else { ps = 5; g = wsp + OFF_G2 + (size_t)b*25*64; }
  float scale = (ps - 1) / 47.f;
  float cy = oy*scale, cx = ox*scale;
  int y0 = (int)cy, x0 = (int)cx;
  float wy = cy - y0, wx = cx - x0;
  int y1 = min(y0+1, ps-1), x1 = min(x0+1, ps-1);
  float a  = g[(y0*ps+x0)*64 + c], bq = g[(y0*ps+x1)*64 + c];
  float cc = g[(y1*ps+x0)*64 + c], d  = g[(y1*ps+x1)*64 + c];
  float v = (a*(1.f-wx) + bq*wx)*(1.f-wy) + (cc*(1.f-wx) + d*wx)*wy;
  wsp[OFF_GC + (((size_t)t*2 + b)*64 + c)*2304 + px] = v;
}

__device__ void gap_body(int blk, float* __restrict__ wsp){
  __shared__ float red[4];
  int c = blk & 63, b = blk >> 6;          // 128 blocks
  const float* src = wsp + OFF_SA + ((size_t)b*64 + c)*2304;
  float s = 0.f;
  for (int i = threadIdx.x; i < 2304; i += 256) s += src[i];
  #pragma unroll
  for (int o = 32; o; o >>= 1) s += __shfl_xor(s, o);
  if ((threadIdx.x & 63) == 0) red[threadIdx.x >> 6] = s;
  __syncthreads();
  if (threadIdx.x == 0)
    wsp[OFF_MEAN + (size_t)b*64 + c] = (red[0]+red[1]+red[2]+red[3]) * (1.f/2304.f);
}

__global__ __launch_bounds__(256) void k_gcup_gap(float* __restrict__ wsp){
  int bx = blockIdx.x;
  if (bx < 3456) gcup_body(bx, wsp);
  else           gap_body(bx - 3456, wsp);
}

// ---------------- K10: SE (gc means analytic from G) ----------------
__global__ __launch_bounds__(256) void k_se(
    const float* __restrict__ w_se1, const float* __restrict__ w_se2,
    const float* __restrict__ w_se3, const float* __restrict__ w_se4,
    float* __restrict__ wsp){
  int b = blockIdx.x; int tid = threadIdx.x;
  int g = tid >> 6, c = tid & 63;
  __shared__ float mean_lds[4][64];
  float mv;
  if (g == 0){
    mv = wsp[OFF_MEAN + (size_t)b*64 + c];
  } else if (g == 3){
    mv = wsp[OFF_G0 + (size_t)b*64 + c];
  } else if (g == 2){
    float w3[3] = {0.f,0.f,0.f};
    for (int o = 0; o < 48; o++){
      float cc = o*(2.f/47.f); int i0 = (int)cc; float f = cc - i0;
      int i1 = min(i0+1, 2);
      w3[i0] += 1.f - f; w3[i1] += f;
    }
    float s = 0.f;
    for (int sy = 0; sy < 3; sy++)
      for (int sx = 0; sx < 3; sx++)
        s += w3[sy]*w3[sx]*wsp[OFF_G1 + ((size_t)b*9 + sy*3 + sx)*64 + c];
    mv = s * (1.f/(48.f*48.f));
  } else {
    float w5[5] = {0.f,0.f,0.f,0.f,0.f};
    for (int o = 0; o < 48; o++){
      float cc = o*(4.f/47.f); int i0 = (int)cc; float f = cc - i0;
      int i1 = min(i0+1, 4);
      w5[i0] += 1.f - f; w5[i1] += f;
    }
    float s = 0.f;
    for (int sy = 0; sy < 5; sy++)
      for (int sx = 0; sx < 5; sx++)
        s += w5[sy]*w5[sx]*wsp[OFF_G2 + ((size_t)b*25 + sy*5 + sx)*64 + c];
    mv = s * (1.f/(48.f*48.f));
  }
  mean_lds[g][c] = mv;
  __syncthreads();
  const float* w = (g == 0) ? w_se1 : (g == 1) ? w_se2 : (g == 2) ? w_se3 : w_se4;
  float acc = 0.f;
  for (int j = 0; j < 64; j++) acc += w[(size_t)c*64 + j]*mean_lds[g][j];
  float sg = 1.f / (1.f + __expf(-acc));
  __shared__ float sh[4][64];
  sh[g][c] = sg;
  __syncthreads();
  float a0 = sh[0][c], a1 = sh[1][c], a2 = sh[2][c], a3 = sh[3][c];
  float mxv = fmaxf(fmaxf(a0, a1), fmaxf(a2, a3));
  float e = __expf(sg - mxv);
  float sum = __expf(a0-mxv) + __expf(a1-mxv) + __expf(a2-mxv) + __expf(a3-mxv);
  wsp[OFF_WGT + ((size_t)b*4 + g)*64 + c] = e / sum;
}

// ---------------- K12: out-head GEMMs, wgt folded, X staged via global_load_lds ----------------
__global__ __launch_bounds__(256) void k_outgemm(
    const float* __restrict__ w0, const float* __restrict__ b0,
    const float* __restrict__ w1, const float* __restrict__ b1,
    const float* __restrict__ w2, const float* __restrict__ b2,
    const float* __restrict__ w3, const float* __restrict__ b3,
    float* __restrict__ wsp){
  __shared__ __align__(16) float wt[64][68];
  __shared__ __align__(16) float xsh[64][64];   // staged activation chunk (16 KB, linear)
  __shared__ float wg[256];
  int cb = blockIdx.x, rb = blockIdx.y;
  int b = cb / 36, hw0 = (cb - b*36)*64;
  const float* wsrc; const float* bsrc; size_t dstoff; int dstC; int row0;
  if (rb < 4){ wsrc = w0 + (size_t)rb*64*256; bsrc = b0 + rb*64; dstoff = OFF_Y0; dstC = 256; row0 = rb*64; }
  else if (rb < 6){ wsrc = w1 + (size_t)(rb-4)*64*256; bsrc = b1 + (rb-4)*64; dstoff = OFF_Y1; dstC = 128; row0 = (rb-4)*64; }
  else if (rb == 6){ wsrc = w2; bsrc = b2; dstoff = OFF_Y2; dstC = 64; row0 = 0; }
  else { wsrc = w3; bsrc = b3; dstoff = OFF_Y3; dstC = 64; row0 = 0; }
  int tid = threadIdx.x;
  int wv_ = tid >> 6, lane = tid & 63;
  wg[tid] = wsp[OFF_WGT + (size_t)b*256 + tid];
  int sr = tid >> 2, sseg = tid & 3;
  int cc0 = (tid & 15)*4, r0 = (tid >> 4)*4;
  float acc[4][4] = {};
  for (int kc = 0; kc < 256; kc += 64){
    __syncthreads();
    {
      int gidx = kc >> 6;
      size_t srcbase = (gidx < 3) ? OFF_GC + ((size_t)(gidx*2 + b))*147456
                                  : OFF_SA + (size_t)b*147456;
      const float* gb = wsp + srcbase + hw0 + (lane & 15)*4;
      int rr = wv_*16 + (lane >> 4);
      #pragma unroll
      for (int i = 0; i < 4; i++)
        GLOAD_LDS(gb + (size_t)(rr + i*4)*2304, &xsh[wv_*16 + i*4][0]);
    }
    #pragma unroll
    for (int i = 0; i < 16; i += 4){
      float4 v = *(const float4*)(wsrc + (size_t)sr*256 + kc + sseg*16 + i);
      int kl = sseg*16 + i;
      wt[kl+0][sr]=v.x*wg[kc+kl+0]; wt[kl+1][sr]=v.y*wg[kc+kl+1];
      wt[kl+2][sr]=v.z*wg[kc+kl+2]; wt[kl+3][sr]=v.w*wg[kc+kl+3];
    }
    __syncthreads();
    #pragma unroll 4
    for (int k = 0; k < 64; k++){
      float4 wv = *(const float4*)&wt[k][r0];
      float4 xv = *(const float4*)&xsh[k][cc0];
      acc[0][0]+=wv.x*xv.x; acc[0][1]+=wv.x*xv.y; acc[0][2]+=wv.x*xv.z; acc[0][3]+=wv.x*xv.w;
      acc[1][0]+=wv.y*xv.x; acc[1][1]+=wv.y*xv.y; acc[1][2]+=wv.y*xv.z; acc[1][3]+=wv.y*xv.w;
      acc[2][0]+=wv.z*xv.x; acc[2][1]+=wv.z*xv.y; acc[2][2]+=wv.z*xv.z; acc[2][3]+=wv.z*xv.w;
      acc[3][0]+=wv.w*xv.x; acc[3][1]+=wv.w*xv.y; acc[3][2]+=wv.w*xv.z; acc[3][3]+=wv.w*xv.w;
    }
  }
  #pragma unroll
  for (int i = 0; i < 4; i++){
    float bi = bsrc[r0+i];
    float4 o;
    o.x = fmaxf(acc[i][0]+bi, 0.f); o.y = fmaxf(acc[i][1]+bi, 0.f);
    o.z = fmaxf(acc[i][2]+bi, 0.f); o.w = fmaxf(acc[i][3]+bi, 0.f);
    *(float4*)(wsp + dstoff + ((size_t)b*dstC + row0 + r0 + i)*2304 + hw0 + cc0) = o;
  }
}

// ---------------- K13: upsample, nt stores; SC>=4 use 6-load source window ----------------
// Generic path (SC=2 only): 16 gather loads per thread.
template<int SC>
__device__ __forceinline__ void up_one(int idx, const float* __restrict__ src, float* __restrict__ dst){
  constexpr int OW = 48*SC, OH = 48*SC;
  constexpr int WQ = OW/4;
  int q = idx % WQ; int rest = idx / WQ;
  int oy = rest % OH; int pc = rest / OH;
  const float* sp = src + (size_t)pc * 2304;
  float cy = fminf(fmaxf((oy + 0.5f)*(1.0f/SC) - 0.5f, 0.f), 47.f);
  int y0 = (int)cy;
  float wy = cy - y0;
  int y1 = min(y0+1, 47);
  const float* r0 = sp + y0*48; const float* r1 = sp + y1*48;
  float outv[4];
  #pragma unroll
  for (int i = 0; i < 4; i++){
    int ox = q*4 + i;
    float cx = fminf(fmaxf((ox + 0.5f)*(1.0f/SC) - 0.5f, 0.f), 47.f);
    int x0 = (int)cx; float wx = cx - x0; int x1 = min(x0+1, 47);
    float a  = r0[x0]*(1.f-wx) + r0[x1]*wx;
    float bq = r1[x0]*(1.f-wx) + r1[x1]*wx;
    outv[i] = a*(1.f-wy) + bq*wy;
  }
  f32x4 o; o[0] = outv[0]; o[1] = outv[1]; o[2] = outv[2]; o[3] = outv[3];
  f32x4* dp = (f32x4*)(dst + (size_t)pc*OH*OW + (size_t)oy*OW + q*4);
  __builtin_nontemporal_store(o, dp);
}

// Specialized (SC in {4,8,16}): a 4-px group spans <1 source px, so x0 of each
// px is xA or xA+1 -> 6 loads (r0/r1 at xA,xA+1,xA+2) cover all corners.
template<int SC>
__device__ __forceinline__ void up_one_w(int idx, const float* __restrict__ src, float* __restrict__ dst){
  constexpr int OW = 48*SC, OH = 48*SC;
  constexpr int WQ = OW/4;
  constexpr float inv = 1.0f/SC;
  int q = idx % WQ; int rest = idx / WQ;
  int oy = rest % OH; int pc = rest / OH;
  const float* sp = src + (size_t)pc * 2304;
  float cy = fminf(fmaxf((oy + 0.5f)*inv - 0.5f, 0.f), 47.f);
  int y0 = (int)cy;
  float wy = cy - y0;
  int y1 = min(y0+1, 47);
  const float* r0 = sp + y0*48; const float* r1 = sp + y1*48;
  int ox0 = q*4;
  float cx0 = fminf(fmaxf((ox0 + 0.5f)*inv - 0.5f, 0.f), 47.f);
  int xA = (int)cx0;
  int xB = min(xA+1, 47), xC = min(xA+2, 47);
  float r0a = r0[xA], r0b = r0[xB], r0c = r0[xC];
  float r1a = r1[xA], r1b = r1[xB], r1c = r1[xC];
  float outv[4];
  #pragma unroll
  for (int i = 0; i < 4; i++){
    float cx = fminf(fmaxf((ox0 + i + 0.5f)*inv - 0.5f, 0.f), 47.f);
    int xi = (int)cx; float wx = cx - xi;
    bool hi = xi > xA;
    float a0 = hi ? r0b : r0a, b0 = hi ? r0c : r0b;
    float a1 = hi ? r1b : r1a, b1 = hi ? r1c : r1b;
    float t0 = a0 + (b0 - a0)*wx;
    float t1 = a1 + (b1 - a1)*wx;
    outv[i] = t0 + (t1 - t0)*wy;
  }
  f32x4 o; o[0] = outv[0]; o[1] = outv[1]; o[2] = outv[2]; o[3] = outv[3];
  f32x4* dp = (f32x4*)(dst + (size_t)pc*OH*OW + (size_t)oy*OW + q*4);
  __builtin_nontemporal_store(o, dp);
}

__global__ __launch_bounds__(256) void k_upsample_all(const float* __restrict__ wsp, float* __restrict__ out){
  int t = blockIdx.x*256 + threadIdx.x;
  if (t < 1179648)       up_one<2>   (t,           wsp + OFF_Y0, out);
  else if (t < 3538944)  up_one_w<4> (t - 1179648, wsp + OFF_Y1, out + 4718592);
  else if (t < 8257536)  up_one_w<8> (t - 3538944, wsp + OFF_Y2, out + 14155776);
  else                   up_one_w<16>(t - 8257536, wsp + OFF_Y3, out + 33030144);
}

// ---------------- launcher ----------------
extern "C" void kernel_launch(void* const* d_in, const int* in_sizes, int n_in,
                              void* d_out, int out_size, void* d_ws, size_t ws_size,
                              hipStream_t stream){
  const float* x     = (const float*)d_in[0];
  const float* w_gc0 = (const float*)d_in[1];
  const float* b_gc0 = (const float*)d_in[2];
  const float* w_gc1 = (const float*)d_in[3];
  const float* b_gc1 = (const float*)d_in[4];
  const float* w_gc2 = (const float*)d_in[5];
  const float* b_gc2 = (const float*)d_in[6];
  const float* w_gc3 = (const float*)d_in[7];
  const float* b_gc3 = (const float*)d_in[8];
  const float* w_q   = (const float*)d_in[9];
  const float* b_q   = (const float*)d_in[10];
  const float* w_k   = (const float*)d_in[11];
  const float* b_k   = (const float*)d_in[12];
  const float* w_v   = (const float*)d_in[13];
  const float* b_v   = (const float*)d_in[14];
  const float* gamma = (const float*)d_in[15];
  const float* w_se1 = (const float*)d_in[16];
  const float* w_se2 = (const float*)d_in[17];
  const float* w_se3 = (const float*)d_in[18];
  const float* w_se4 = (const float*)d_in[19];
  const float* w_out0 = (const float*)d_in[20];
  const float* b_out0 = (const float*)d_in[21];
  const float* w_out1 = (const float*)d_in[22];
  const float* b_out1 = (const float*)d_in[23];
  const float* w_out2 = (const float*)d_in[24];
  const float* b_out2 = (const float*)d_in[25];
  const float* w_out3 = (const float*)d_in[26];
  const float* b_out3 = (const float*)d_in[27];
  float* wsp = (float*)d_ws;
  float* out = (float*)d_out;

  k_pool     <<<1024, 256, 0, stream>>>(x, wsp);
  k_gcconv   <<<70,   256, 0, stream>>>(w_gc0,b_gc0,w_gc1,b_gc1,w_gc2,b_gc2, wsp);
  k_sgemm_qkv<<<144,  256, 0, stream>>>(x, w_gc3, b_gc3, w_q,b_q,w_k,b_k,w_v,b_v, wsp);
  k_attn     <<<dim3(144,2), 256, 0, stream>>>(wsp, gamma);
  k_gcup_gap <<<3584, 256, 0, stream>>>(wsp);
  k_se       <<<2,    256, 0, stream>>>(w_se1,w_se2,w_se3,w_se4, wsp);
  k_outgemm  <<<dim3(72,8), 256, 0, stream>>>(w_out0,b_out0,w_out1,b_out1,w_out2,b_out2,w_out3,b_out3, wsp);
  k_upsample_all<<<105984, 256, 0, stream>>>(wsp, out);
}

// Round 14
// 193.372 us; speedup vs baseline: 1.9217x; 1.0446x over previous
//
#include <hip/hip_runtime.h>
#include <hip/hip_bf16.h>
#include <hip/hip_fp16.h>

// B=2, Cin=512, C=64, H=W=48, N=2304 spatial, 4608 total columns.
// R14 = exact R13 pipeline (202.0us best) + ONE change:
//   upsample rewritten as LDS row-band + fully-contiguous nt stores.
//   (R7's LDS variant failed pre-nt AND with 48B-strided stores; this is the
//   clean test: all interpolation reads from LDS, 1KB-dense nt store/pass.)
// History: up T: 138 (R6 probe) -> 125 (nt, R9) -> 112 (6-load window, R13).

typedef __attribute__((ext_vector_type(8))) short short8;
typedef __attribute__((ext_vector_type(4))) float f32x4;

#define GLOAD_LDS(gsrc, ldst) \
  __builtin_amdgcn_global_load_lds((const __attribute__((address_space(1))) void*)(gsrc), \
                                   (__attribute__((address_space(3))) void*)(ldst), 16, 0, 0)

// ---------------- ws layout (float offsets) ----------------
static constexpr size_t OFF_P1 = 0;                       // [2][512]
static constexpr size_t OFF_P3 = OFF_P1 + 2*512;          // [2*9][512]
static constexpr size_t OFF_P5 = OFF_P3 + 18*512;         // [2*25][512]
static constexpr size_t OFF_G0 = OFF_P5 + 50*512;         // [2*1][64]
static constexpr size_t OFF_G1 = OFF_G0 + 2*64;           // [2*9][64]
static constexpr size_t OFF_G2 = OFF_G1 + 18*64;          // [2*25][64]
static constexpr size_t OFF_S  = OFF_G2 + 50*64;          // [2][64][2304] f32
static constexpr size_t OFF_Q  = OFF_S  + 294912;         // [2][8][2304] f32
static constexpr size_t OFF_K  = OFF_Q  + 36864;          // [2][8][2304] f32
static constexpr size_t OFF_V  = OFF_K  + 36864;          // bf16 [2][64][2304]
static constexpr size_t OFF_SA = OFF_V  + 294912;         // [2][64][2304] f32
static constexpr size_t OFF_GC = OFF_SA + 294912;         // [3][2][64][2304] f32
static constexpr size_t OFF_MEAN = OFF_GC + 3*294912;     // [2][64]
static constexpr size_t OFF_WGT  = OFF_MEAN + 512;        // [2][4][64]
static constexpr size_t OFF_Y0 = OFF_WGT + 512;           // [2][256][2304]
static constexpr size_t OFF_Y1 = OFF_Y0 + 1179648;        // [2][128][2304]
static constexpr size_t OFF_Y2 = OFF_Y1 + 589824;         // [2][64][2304]
static constexpr size_t OFF_Y3 = OFF_Y2 + 294912;         // [2][64][2304]

// ---------------- K1: adaptive pools (1,3,5) ----------------
__global__ __launch_bounds__(256) void k_pool(const float* __restrict__ x, float* __restrict__ wsp){
  __shared__ float pl[2304];
  __shared__ float red[4];
  int bc = blockIdx.x;            // b*512 + cin
  int b = bc >> 9, cin = bc & 511;
  const float* src = x + (size_t)bc * 2304;
  int t = threadIdx.x;
  float ls = 0.f;
  #pragma unroll
  for (int j = 0; j < 9; j++){ int i = t + j*256; float v = src[i]; pl[i] = v; ls += v; }
  #pragma unroll
  for (int o = 32; o; o >>= 1) ls += __shfl_xor(ls, o);
  if ((t & 63) == 0) red[t >> 6] = ls;
  __syncthreads();
  if (t == 0) wsp[OFF_P1 + (size_t)b*512 + cin] = (red[0]+red[1]+red[2]+red[3]) * (1.f/2304.f);
  if (t < 9){
    int ry = t/3, rx = t%3; float sm = 0.f;
    for (int yy = 0; yy < 16; yy++)
      for (int xx = 0; xx < 16; xx++) sm += pl[(ry*16+yy)*48 + rx*16+xx];
    wsp[OFF_P3 + ((size_t)b*9 + t)*512 + cin] = sm * (1.f/256.f);
  } else if (t < 34){
    int j = t - 9; int ry = j/5, rx = j%5;
    int hs = (ry*48)/5, he = ((ry+1)*48+4)/5, cs = (rx*48)/5, ce = ((rx+1)*48+4)/5;
    float sm = 0.f;
    for (int yy = hs; yy < he; yy++)
      for (int xx = cs; xx < ce; xx++) sm += pl[yy*48+xx];
    wsp[OFF_P5 + ((size_t)b*25 + j)*512 + cin] = sm / (float)((he-hs)*(ce-cs));
  }
}

// ---------------- K2: tiny 64x512 convs on pooled cols ----------------
__global__ __launch_bounds__(256) void k_gcconv(
    const float* __restrict__ w0, const float* __restrict__ b0,
    const float* __restrict__ w1, const float* __restrict__ b1,
    const float* __restrict__ w2, const float* __restrict__ b2,
    float* __restrict__ wsp){
  int col = blockIdx.x;          // 0..69
  const float* w; const float* bias; const float* pool; float* dst;
  if (col < 2){ w = w0; bias = b0; pool = wsp + OFF_P1 + (size_t)col*512; dst = wsp + OFF_G0 + (size_t)col*64; }
  else if (col < 20){ int c = col-2;  w = w1; bias = b1; pool = wsp + OFF_P3 + (size_t)c*512; dst = wsp + OFF_G1 + (size_t)c*64; }
  else              { int c = col-20; w = w2; bias = b2; pool = wsp + OFF_P5 + (size_t)c*512; dst = wsp + OFF_G2 + (size_t)c*64; }
  int t = threadIdx.x; int r = t >> 2, qd = t & 3;
  const float* wr = w + (size_t)r*512 + qd*128;
  const float* pr = pool + qd*128;
  float acc = 0.f;
  #pragma unroll 8
  for (int k = 0; k < 128; k += 4){
    float4 wv = *(const float4*)(wr + k); float4 pv = *(const float4*)(pr + k);
    acc += wv.x*pv.x + wv.y*pv.y + wv.z*pv.z + wv.w*pv.w;
  }
  acc += __shfl_xor(acc, 1); acc += __shfl_xor(acc, 2);
  if (qd == 0) dst[r] = fmaxf(acc + bias[r], 0.f);
}

// ---------------- K3: s = relu(Wgc3.x+b) + fused QKV, X staged via global_load_lds ----------------
__global__ __launch_bounds__(256) void k_sgemm_qkv(const float* __restrict__ x,
    const float* __restrict__ w, const float* __restrict__ bias,
    const float* __restrict__ wq, const float* __restrict__ bq,
    const float* __restrict__ wk, const float* __restrict__ bk,
    const float* __restrict__ wv, const float* __restrict__ bv,
    float* __restrict__ wsp){
  __shared__ __align__(16) float wt[64][66];     // [k][row]
  __shared__ __align__(16) float xs[64][32];     // [k][col] staged X chunk
  __shared__ __align__(16) float s_lds[64][36];  // [chan][col]
  __shared__ float wq_lds[80][64];
  __shared__ float bqkv[80];
  int cb = blockIdx.x;
  int b = cb / 72, hw0 = (cb - b*72)*32;
  int tid = threadIdx.x;
  int wv_ = tid >> 6, lane = tid & 63;
  for (int i = tid; i < 5120; i += 256){
    int row = i >> 6, k = i & 63;
    wq_lds[row][k] = (row < 8) ? wq[(size_t)row*64 + k]
                   : (row < 16) ? wk[(size_t)(row-8)*64 + k]
                                : wv[(size_t)(row-16)*64 + k];
  }
  if (tid < 80) bqkv[tid] = (tid < 8) ? bq[tid] : (tid < 16) ? bk[tid-8] : bv[tid-16];
  int sr = tid >> 2, sseg = tid & 3;
  int cc0 = (tid & 7)*4, r0 = (tid >> 3)*2;
  const float* xb = x + (size_t)b*512*2304 + hw0;
  float acc[2][4] = {};
  for (int kc = 0; kc < 512; kc += 64){
    __syncthreads();
    {
      int rr0 = wv_*16 + (lane >> 3);
      const float* g0 = xb + (size_t)(kc + rr0)*2304 + (lane & 7)*4;
      const float* g1 = xb + (size_t)(kc + rr0 + 8)*2304 + (lane & 7)*4;
      GLOAD_LDS(g0, &xs[wv_*16][0]);
      GLOAD_LDS(g1, &xs[wv_*16 + 8][0]);
    }
    #pragma unroll
    for (int i = 0; i < 16; i += 4){
      float4 v = *(const float4*)(w + (size_t)sr*512 + kc + sseg*16 + i);
      wt[sseg*16+i+0][sr]=v.x; wt[sseg*16+i+1][sr]=v.y;
      wt[sseg*16+i+2][sr]=v.z; wt[sseg*16+i+3][sr]=v.w;
    }
    __syncthreads();
    #pragma unroll 4
    for (int k = 0; k < 64; k++){
      float2 wv2 = *(const float2*)&wt[k][r0];
      float4 xv = *(const float4*)&xs[k][cc0];
      acc[0][0]+=wv2.x*xv.x; acc[0][1]+=wv2.x*xv.y; acc[0][2]+=wv2.x*xv.z; acc[0][3]+=wv2.x*xv.w;
      acc[1][0]+=wv2.y*xv.x; acc[1][1]+=wv2.y*xv.y; acc[1][2]+=wv2.y*xv.z; acc[1][3]+=wv2.y*xv.w;
    }
  }
  #pragma unroll
  for (int i = 0; i < 2; i++){
    float bi = bias[r0+i];
    float4 o;
    o.x = fmaxf(acc[i][0]+bi, 0.f); o.y = fmaxf(acc[i][1]+bi, 0.f);
    o.z = fmaxf(acc[i][2]+bi, 0.f); o.w = fmaxf(acc[i][3]+bi, 0.f);
    *(float4*)(wsp + OFF_S + ((size_t)b*64 + r0+i)*2304 + hw0 + cc0) = o;
    *(float4*)&s_lds[r0+i][cc0] = o;
  }
  __syncthreads();
  int col = tid & 31, rgrp = tid >> 5;
  float a2[10];
  #pragma unroll
  for (int i = 0; i < 10; i++) a2[i] = bqkv[rgrp*10 + i];
  for (int k = 0; k < 64; k++){
    float sv = s_lds[k][col];
    #pragma unroll
    for (int i = 0; i < 10; i++) a2[i] += wq_lds[rgrp*10 + i][k]*sv;
  }
  __hip_bfloat16* Vb = reinterpret_cast<__hip_bfloat16*>(wsp + OFF_V);
  int hw = hw0 + col;
  #pragma unroll
  for (int i = 0; i < 10; i++){
    int r = rgrp*10 + i;
    if (r < 8)       wsp[OFF_Q + (size_t)b*18432 + (size_t)r*2304 + hw] = a2[i];
    else if (r < 16) wsp[OFF_K + (size_t)b*18432 + (size_t)(r-8)*2304 + hw] = a2[i];
    else             Vb[(size_t)b*147456 + (size_t)(r-16)*2304 + hw] = __float2bfloat16(a2[i]);
  }
}

// ---------------- K4: flash attention ----------------
__global__ __launch_bounds__(256) void k_attn(float* __restrict__ wsp, const float* __restrict__ gamma){
  int mb = blockIdx.x * 16;
  int b  = blockIdx.y;
  int t = threadIdx.x;
  int w = t >> 6, lane = t & 63;
  int arow = lane & 15, kg = lane >> 4;
  __shared__ float qs[16][8];
  __shared__ __align__(16) unsigned short plds[16][2312];
  __shared__ float redM[4][16], redS[4][16];
  __shared__ float tile[16][68];
  const float* Qp = wsp + OFF_Q + (size_t)b*18432;
  const float* Kp = wsp + OFF_K + (size_t)b*18432;
  if (t < 128) qs[t>>3][t&7] = Qp[(size_t)(t&7)*2304 + mb + (t>>3)];
  __syncthreads();
  float k8[9][8];
  #pragma unroll
  for (int j = 0; j < 9; j++){
    int n = j*256 + t;
    #pragma unroll
    for (int c = 0; c < 8; c++) k8[j][c] = Kp[(size_t)c*2304 + n];
  }
  float mx[16], ssum[16];
  #pragma unroll
  for (int m = 0; m < 16; m++){
    float q0=qs[m][0], q1=qs[m][1], q2=qs[m][2], q3=qs[m][3];
    float q4=qs[m][4], q5=qs[m][5], q6=qs[m][6], q7=qs[m][7];
    float lmx = -1e30f, ls = 0.f;
    #pragma unroll
    for (int j = 0; j < 9; j++){
      float l = q0*k8[j][0]+q1*k8[j][1]+q2*k8[j][2]+q3*k8[j][3]
              + q4*k8[j][4]+q5*k8[j][5]+q6*k8[j][6]+q7*k8[j][7];
      __half hv = __float2half(l);
      plds[m][j*256 + t] = __half_as_ushort(hv);
      float mo = lmx;
      lmx = fmaxf(lmx, l);
      ls = ls*__expf(mo - lmx) + __expf(l - lmx);
    }
    mx[m] = lmx; ssum[m] = ls;
  }
  #pragma unroll
  for (int m = 0; m < 16; m++){
    float M = mx[m], S = ssum[m];
    #pragma unroll
    for (int off = 32; off; off >>= 1){
      float oM = __shfl_xor(M, off), oS = __shfl_xor(S, off);
      float nM = fmaxf(M, oM);
      S = S*__expf(M - nM) + oS*__expf(oM - nM);
      M = nM;
    }
    if (lane == 0){ redM[w][m] = M; redS[w][m] = S; }
  }
  __syncthreads();
  float Mf[16], invS[16];
  #pragma unroll
  for (int m = 0; m < 16; m++){
    float M0 = redM[0][m], M1 = redM[1][m], M2 = redM[2][m], M3 = redM[3][m];
    float M = fmaxf(fmaxf(M0, M1), fmaxf(M2, M3));
    float S = redS[0][m]*__expf(M0-M) + redS[1][m]*__expf(M1-M)
            + redS[2][m]*__expf(M2-M) + redS[3][m]*__expf(M3-M);
    Mf[m] = M; invS[m] = 1.f/S;
  }
  const short* Vb = (const short*)(wsp + OFF_V) + (size_t)b*147456 + (size_t)(w*16 + arow)*2304;
  f32x4 acc = {0.f, 0.f, 0.f, 0.f};
  for (int j = 0; j < 9; j++){
    int n = j*256 + t;
    #pragma unroll
    for (int m = 0; m < 16; m++){
      float l = __half2float(__ushort_as_half(plds[m][n]));
      float p = __expf(l - Mf[m]) * invS[m];
      __hip_bfloat16 pb = __float2bfloat16(p);
      plds[m][n] = *(unsigned short*)&pb;
    }
    __syncthreads();
    #pragma unroll
    for (int ks = 0; ks < 8; ks++){
      int nb = j*256 + ks*32 + kg*8;
      short8 a  = *(const short8*)&plds[arow][nb];
      short8 bv = *(const short8*)(Vb + nb);
      acc = __builtin_amdgcn_mfma_f32_16x16x32_bf16(a, bv, acc, 0, 0, 0);
    }
  }
  #pragma unroll
  for (int r = 0; r < 4; r++) tile[kg*4 + r][w*16 + arow] = acc[r];
  __syncthreads();
  int c = t >> 2, mq = t & 3;
  float g = gamma[0];
  const float* Sp = wsp + OFF_S + (size_t)b*147456 + (size_t)c*2304 + mb + mq*4;
  float4 s4 = *(const float4*)Sp;
  float4 o;
  o.x = g*tile[mq*4+0][c] + s4.x;
  o.y = g*tile[mq*4+1][c] + s4.y;
  o.z = g*tile[mq*4+2][c] + s4.z;
  o.w = g*tile[mq*4+3][c] + s4.w;
  *(float4*)(wsp + OFF_SA + (size_t)b*147456 + (size_t)c*2304 + mb + mq*4) = o;
}

// ---------------- K8+K9 merged: gcup (0..3455) + gap (3456..3583) ----------------
__device__ void gcup_body(int u, float* __restrict__ wsp){
  int px = (u % 9)*256 + threadIdx.x;      // 0..2303
  int pb = u / 9;                          // t*128 + b*64 + c
  int c = pb & 63, b = (pb >> 6) & 1, t = pb >> 7;
  int oy = px / 48, ox = px - oy*48;
  int ps; const float* g;
  if (t == 0){ ps = 1; g = wsp + OFF_G0 + (size_t)b*64; }
  else if (t == 1){ ps = 3; g = wsp + OFF_G1 + (size_t)b*9*64; }
  else { ps = 5; g = wsp + OFF_G2 + (size_t)b*25*64; }
  float scale = (ps - 1) / 47.f;
  float cy = oy*scale, cx = ox*scale;
  int y0 = (int)cy, x0 = (int)cx;
  float wy = cy - y0, wx = cx - x0;
  int y1 = min(y0+1, ps-1), x1 = min(x0+1, ps-1);
  float a  = g[(y0*ps+x0)*64 + c], bq = g[(y0*ps+x1)*64 + c];
  float cc = g[(y1*ps+x0)*64 + c], d  = g[(y1*ps+x1)*64 + c];
  float v = (a*(1.f-wx) + bq*wx)*(1.f-wy) + (cc*(1.f-wx) + d*wx)*wy;
  wsp[OFF_GC + (((size_t)t*2 + b)*64 + c)*2304 + px] = v;
}

__device__ void gap_body(int blk, float* __restrict__ wsp){
  __shared__ float red[4];
  int c = blk & 63, b = blk >> 6;          // 128 blocks
  const float* src = wsp + OFF_SA + ((size_t)b*64 + c)*2304;
  float s = 0.f;
  for (int i = threadIdx.x; i < 2304; i += 256) s += src[i];
  #pragma unroll
  for (int o = 32; o; o >>= 1) s += __shfl_xor(s, o);
  if ((threadIdx.x & 63) == 0) red[threadIdx.x >> 6] = s;
  __syncthreads();
  if (threadIdx.x == 0)
    wsp[OFF_MEAN + (size_t)b*64 + c] = (red[0]+red[1]+red[2]+red[3]) * (1.f/2304.f);
}

__global__ __launch_bounds__(256) void k_gcup_gap(float* __restrict__ wsp){
  int bx = blockIdx.x;
  if (bx < 3456) gcup_body(bx, wsp);
  else           gap_body(bx - 3456, wsp);
}

// ---------------- K10: SE (gc means analytic from G) ----------------
__global__ __launch_bounds__(256) void k_se(
    const float* __restrict__ w_se1, const float* __restrict__ w_se2,
    const float* __restrict__ w_se3, const float* __restrict__ w_se4,
    float* __restrict__ wsp){
  int b = blockIdx.x; int tid = threadIdx.x;
  int g = tid >> 6, c = tid & 63;
  __shared__ float mean_lds[4][64];
  float mv;
  if (g == 0){
    mv = wsp[OFF_MEAN + (size_t)b*64 + c];
  } else if (g == 3){
    mv = wsp[OFF_G0 + (size_t)b*64 + c];
  } else if (g == 2){
    float w3[3] = {0.f,0.f,0.f};
    for (int o = 0; o < 48; o++){
      float cc = o*(2.f/47.f); int i0 = (int)cc; float f = cc - i0;
      int i1 = min(i0+1, 2);
      w3[i0] += 1.f - f; w3[i1] += f;
    }
    float s = 0.f;
    for (int sy = 0; sy < 3; sy++)
      for (int sx = 0; sx < 3; sx++)
        s += w3[sy]*w3[sx]*wsp[OFF_G1 + ((size_t)b*9 + sy*3 + sx)*64 + c];
    mv = s * (1.f/(48.f*48.f));
  } else {
    float w5[5] = {0.f,0.f,0.f,0.f,0.f};
    for (int o = 0; o < 48; o++){
      float cc = o*(4.f/47.f); int i0 = (int)cc; float f = cc - i0;
      int i1 = min(i0+1, 4);
      w5[i0] += 1.f - f; w5[i1] += f;
    }
    float s = 0.f;
    for (int sy = 0; sy < 5; sy++)
      for (int sx = 0; sx < 5; sx++)
        s += w5[sy]*w5[sx]*wsp[OFF_G2 + ((size_t)b*25 + sy*5 + sx)*64 + c];
    mv = s * (1.f/(48.f*48.f));
  }
  mean_lds[g][c] = mv;
  __syncthreads();
  const float* w = (g == 0) ? w_se1 : (g == 1) ? w_se2 : (g == 2) ? w_se3 : w_se4;
  float acc = 0.f;
  for (int j = 0; j < 64; j++) acc += w[(size_t)c*64 + j]*mean_lds[g][j];
  float sg = 1.f / (1.f + __expf(-acc));
  __shared__ float sh[4][64];
  sh[g][c] = sg;
  __syncthreads();
  float a0 = sh[0][c], a1 = sh[1][c], a2 = sh[2][c], a3 = sh[3][c];
  float mxv = fmaxf(fmaxf(a0, a1), fmaxf(a2, a3));
  float e = __expf(sg - mxv);
  float sum = __expf(a0-mxv) + __expf(a1-mxv) + __expf(a2-mxv) + __expf(a3-mxv);
  wsp[OFF_WGT + ((size_t)b*4 + g)*64 + c] = e / sum;
}

// ---------------- K12: out-head GEMMs, wgt folded, X staged via global_load_lds ----------------
__global__ __launch_bounds__(256) void k_outgemm(
    const float* __restrict__ w0, const float* __restrict__ b0,
    const float* __restrict__ w1, const float* __restrict__ b1,
    const float* __restrict__ w2, const float* __restrict__ b2,
    const float* __restrict__ w3, const float* __restrict__ b3,
    float* __restrict__ wsp){
  __shared__ __align__(16) float wt[64][68];
  __shared__ __align__(16) float xsh[64][64];   // staged activation chunk (16 KB, linear)
  __shared__ float wg[256];
  int cb = blockIdx.x, rb = blockIdx.y;
  int b = cb / 36, hw0 = (cb - b*36)*64;
  const float* wsrc; const float* bsrc; size_t dstoff; int dstC; int row0;
  if (rb < 4){ wsrc = w0 + (size_t)rb*64*256; bsrc = b0 + rb*64; dstoff = OFF_Y0; dstC = 256; row0 = rb*64; }
  else if (rb < 6){ wsrc = w1 + (size_t)(rb-4)*64*256; bsrc = b1 + (rb-4)*64; dstoff = OFF_Y1; dstC = 128; row0 = (rb-4)*64; }
  else if (rb == 6){ wsrc = w2; bsrc = b2; dstoff = OFF_Y2; dstC = 64; row0 = 0; }
  else { wsrc = w3; bsrc = b3; dstoff = OFF_Y3; dstC = 64; row0 = 0; }
  int tid = threadIdx.x;
  int wv_ = tid >> 6, lane = tid & 63;
  wg[tid] = wsp[OFF_WGT + (size_t)b*256 + tid];
  int sr = tid >> 2, sseg = tid & 3;
  int cc0 = (tid & 15)*4, r0 = (tid >> 4)*4;
  float acc[4][4] = {};
  for (int kc = 0; kc < 256; kc += 64){
    __syncthreads();
    {
      int gidx = kc >> 6;
      size_t srcbase = (gidx < 3) ? OFF_GC + ((size_t)(gidx*2 + b))*147456
                                  : OFF_SA + (size_t)b*147456;
      const float* gb = wsp + srcbase + hw0 + (lane & 15)*4;
      int rr = wv_*16 + (lane >> 4);
      #pragma unroll
      for (int i = 0; i < 4; i++)
        GLOAD_LDS(gb + (size_t)(rr + i*4)*2304, &xsh[wv_*16 + i*4][0]);
    }
    #pragma unroll
    for (int i = 0; i < 16; i += 4){
      float4 v = *(const float4*)(wsrc + (size_t)sr*256 + kc + sseg*16 + i);
      int kl = sseg*16 + i;
      wt[kl+0][sr]=v.x*wg[kc+kl+0]; wt[kl+1][sr]=v.y*wg[kc+kl+1];
      wt[kl+2][sr]=v.z*wg[kc+kl+2]; wt[kl+3][sr]=v.w*wg[kc+kl+3];
    }
    __syncthreads();
    #pragma unroll 4
    for (int k = 0; k < 64; k++){
      float4 wv = *(const float4*)&wt[k][r0];
      float4 xv = *(const float4*)&xsh[k][cc0];
      acc[0][0]+=wv.x*xv.x; acc[0][1]+=wv.x*xv.y; acc[0][2]+=wv.x*xv.z; acc[0][3]+=wv.x*xv.w;
      acc[1][0]+=wv.y*xv.x; acc[1][1]+=wv.y*xv.y; acc[1][2]+=wv.y*xv.z; acc[1][3]+=wv.y*xv.w;
      acc[2][0]+=wv.z*xv.x; acc[2][1]+=wv.z*xv.y; acc[2][2]+=wv.z*xv.z; acc[2][3]+=wv.z*xv.w;
      acc[3][0]+=wv.w*xv.x; acc[3][1]+=wv.w*xv.y; acc[3][2]+=wv.w*xv.z; acc[3][3]+=wv.w*xv.w;
    }
  }
  #pragma unroll
  for (int i = 0; i < 4; i++){
    float bi = bsrc[r0+i];
    float4 o;
    o.x = fmaxf(acc[i][0]+bi, 0.f); o.y = fmaxf(acc[i][1]+bi, 0.f);
    o.z = fmaxf(acc[i][2]+bi, 0.f); o.w = fmaxf(acc[i][3]+bi, 0.f);
    *(float4*)(wsp + dstoff + ((size_t)b*dstC + row0 + r0 + i)*2304 + hw0 + cc0) = o;
  }
}

// ---------------- K13: upsample, LDS row-band + contiguous nt stores ----------------
// Block = (plane, band of RPB output rows). Stage NR source rows (<=3.4KB LDS,
// coalesced), then 3 passes: each pass stores 256 consecutive float4s (1KB/wave
// fully dense, nt). All interpolation reads come from LDS.
// Window proofs: (SC,RPB,NR) = (2,32,18),(4,16,6),(8,8,3),(16,4,3):
//   y1max - y0min <= NR-1 for every band (y clamps only shrink the offset).
template<int SC, int RPB, int NR>
__device__ __forceinline__ void up_band(int bi, const float* __restrict__ src,
                                        float* __restrict__ dst, float (*srow)[48]){
  constexpr int OW = 48*SC, OH = 48*SC, OW4 = OW/4;
  constexpr float inv = 1.0f/SC;
  constexpr int BANDS = OH/RPB;
  int pc = bi / BANDS, band = bi - pc*BANDS;
  int r0b = band * RPB;
  const float* sp = src + (size_t)pc * 2304;
  int y0min = (int)fmaxf((r0b + 0.5f)*inv - 0.5f, 0.f);
  int t = threadIdx.x;
  for (int i = t; i < NR*48; i += 256){
    int r = i / 48, cc = i - r*48;
    srow[r][cc] = sp[min(y0min + r, 47)*48 + cc];
  }
  __syncthreads();
  float* dbase = dst + (size_t)pc*OH*OW + (size_t)r0b*OW;
  #pragma unroll
  for (int p = 0; p < 3; p++){
    int local = p*256 + t;                 // f4 index within band (row-major)
    int lrow = local / OW4;
    int q = local - lrow*OW4;
    int oy = r0b + lrow;
    float cy = fminf(fmaxf((oy + 0.5f)*inv - 0.5f, 0.f), 47.f);
    int y0 = (int)cy; float wy = cy - y0;
    int y1 = min(y0 + 1, 47);
    const float* s0 = srow[min(y0 - y0min, NR-1)];
    const float* s1 = srow[min(y1 - y0min, NR-1)];
    float ov[4];
    #pragma unroll
    for (int i = 0; i < 4; i++){
      float cx = fminf(fmaxf((q*4 + i + 0.5f)*inv - 0.5f, 0.f), 47.f);
      int x0 = (int)cx; float wx = cx - x0;
      int x1 = min(x0 + 1, 47);
      float a = s0[x0] + (s0[x1] - s0[x0])*wx;
      float b = s1[x0] + (s1[x1] - s1[x0])*wx;
      ov[i] = a + (b - a)*wy;
    }
    f32x4 o; o[0]=ov[0]; o[1]=ov[1]; o[2]=ov[2]; o[3]=ov[3];
    __builtin_nontemporal_store(o, (f32x4*)(dbase + (size_t)local*4));
  }
}

__global__ __launch_bounds__(256) void k_upsample_all(const float* __restrict__ wsp, float* __restrict__ out){
  __shared__ float srow[18][48];
  int b = blockIdx.x;
  // head0: 512 planes x 3 bands   = 1536
  // head1: 256 planes x 12 bands  = 3072   (-> 4608)
  // head2: 128 planes x 48 bands  = 6144   (-> 10752)
  // head3: 128 planes x 192 bands = 24576  (-> 35328)
  if (b < 1536)        up_band<2,32,18>(b,         wsp + OFF_Y0, out,            srow);
  else if (b < 4608)   up_band<4,16,6> (b - 1536,  wsp + OFF_Y1, out + 4718592,  srow);
  else if (b < 10752)  up_band<8,8,3>  (b - 4608,  wsp + OFF_Y2, out + 14155776, srow);
  else                 up_band<16,4,3> (b - 10752, wsp + OFF_Y3, out + 33030144, srow);
}

// ---------------- launcher ----------------
extern "C" void kernel_launch(void* const* d_in, const int* in_sizes, int n_in,
                              void* d_out, int out_size, void* d_ws, size_t ws_size,
                              hipStream_t stream){
  const float* x     = (const float*)d_in[0];
  const float* w_gc0 = (const float*)d_in[1];
  const float* b_gc0 = (const float*)d_in[2];
  const float* w_gc1 = (const float*)d_in[3];
  const float* b_gc1 = (const float*)d_in[4];
  const float* w_gc2 = (const float*)d_in[5];
  const float* b_gc2 = (const float*)d_in[6];
  const float* w_gc3 = (const float*)d_in[7];
  const float* b_gc3 = (const float*)d_in[8];
  const float* w_q   = (const float*)d_in[9];
  const float* b_q   = (const float*)d_in[10];
  const float* w_k   = (const float*)d_in[11];
  const float* b_k   = (const float*)d_in[12];
  const float* w_v   = (const float*)d_in[13];
  const float* b_v   = (const float*)d_in[14];
  const float* gamma = (const float*)d_in[15];
  const float* w_se1 = (const float*)d_in[16];
  const float* w_se2 = (const float*)d_in[17];
  const float* w_se3 = (const float*)d_in[18];
  const float* w_se4 = (const float*)d_in[19];
  const float* w_out0 = (const float*)d_in[20];
  const float* b_out0 = (const float*)d_in[21];
  const float* w_out1 = (const float*)d_in[22];
  const float* b_out1 = (const float*)d_in[23];
  const float* w_out2 = (const float*)d_in[24];
  const float* b_out2 = (const float*)d_in[25];
  const float* w_out3 = (const float*)d_in[26];
  const float* b_out3 = (const float*)d_in[27];
  float* wsp = (float*)d_ws;
  float* out = (float*)d_out;

  k_pool     <<<1024, 256, 0, stream>>>(x, wsp);
  k_gcconv   <<<70,   256, 0, stream>>>(w_gc0,b_gc0,w_gc1,b_gc1,w_gc2,b_gc2, wsp);
  k_sgemm_qkv<<<144,  256, 0, stream>>>(x, w_gc3, b_gc3, w_q,b_q,w_k,b_k,w_v,b_v, wsp);
  k_attn     <<<dim3(144,2), 256, 0, stream>>>(wsp, gamma);
  k_gcup_gap <<<3584, 256, 0, stream>>>(wsp);
  k_se       <<<2,    256, 0, stream>>>(w_se1,w_se2,w_se3,w_se4, wsp);
  k_outgemm  <<<dim3(72,8), 256, 0, stream>>>(w_out0,b_out0,w_out1,b_out1,w_out2,b_out2,w_out3,b_out3, wsp);
  k_upsample_all<<<35328, 256, 0, stream>>>(wsp, out);
}

// Round 15
// 184.186 us; speedup vs baseline: 2.0175x; 1.0499x over previous
//
#include <hip/hip_runtime.h>
#include <hip/hip_bf16.h>
#include <hip/hip_fp16.h>

// B=2, Cin=512, C=64, H=W=48, N=2304 spatial, 4608 total columns.
// R15 = exact R14 pipeline (193.4us best) + ONE change:
//   k_gcconv merged into the attn launch (k_attn_gc, 358 blocks: 0-287 attn,
//   288-357 gcconv). Same pairing as R5's launchC; R12 proved demux merges
//   benign; R11's poison was the 2-block se-fold (de-parallelized reduction).
// Upsample history: 138 -> 125 (nt) -> 112 (6-load) -> ~103 (LDS band, R14).

typedef __attribute__((ext_vector_type(8))) short short8;
typedef __attribute__((ext_vector_type(4))) float f32x4;

#define GLOAD_LDS(gsrc, ldst) \
  __builtin_amdgcn_global_load_lds((const __attribute__((address_space(1))) void*)(gsrc), \
                                   (__attribute__((address_space(3))) void*)(ldst), 16, 0, 0)

// ---------------- ws layout (float offsets) ----------------
static constexpr size_t OFF_P1 = 0;                       // [2][512]
static constexpr size_t OFF_P3 = OFF_P1 + 2*512;          // [2*9][512]
static constexpr size_t OFF_P5 = OFF_P3 + 18*512;         // [2*25][512]
static constexpr size_t OFF_G0 = OFF_P5 + 50*512;         // [2*1][64]
static constexpr size_t OFF_G1 = OFF_G0 + 2*64;           // [2*9][64]
static constexpr size_t OFF_G2 = OFF_G1 + 18*64;          // [2*25][64]
static constexpr size_t OFF_S  = OFF_G2 + 50*64;          // [2][64][2304] f32
static constexpr size_t OFF_Q  = OFF_S  + 294912;         // [2][8][2304] f32
static constexpr size_t OFF_K  = OFF_Q  + 36864;          // [2][8][2304] f32
static constexpr size_t OFF_V  = OFF_K  + 36864;          // bf16 [2][64][2304]
static constexpr size_t OFF_SA = OFF_V  + 294912;         // [2][64][2304] f32
static constexpr size_t OFF_GC = OFF_SA + 294912;         // [3][2][64][2304] f32
static constexpr size_t OFF_MEAN = OFF_GC + 3*294912;     // [2][64]
static constexpr size_t OFF_WGT  = OFF_MEAN + 512;        // [2][4][64]
static constexpr size_t OFF_Y0 = OFF_WGT + 512;           // [2][256][2304]
static constexpr size_t OFF_Y1 = OFF_Y0 + 1179648;        // [2][128][2304]
static constexpr size_t OFF_Y2 = OFF_Y1 + 589824;         // [2][64][2304]
static constexpr size_t OFF_Y3 = OFF_Y2 + 294912;         // [2][64][2304]

// ---------------- K1: adaptive pools (1,3,5) ----------------
__global__ __launch_bounds__(256) void k_pool(const float* __restrict__ x, float* __restrict__ wsp){
  __shared__ float pl[2304];
  __shared__ float red[4];
  int bc = blockIdx.x;            // b*512 + cin
  int b = bc >> 9, cin = bc & 511;
  const float* src = x + (size_t)bc * 2304;
  int t = threadIdx.x;
  float ls = 0.f;
  #pragma unroll
  for (int j = 0; j < 9; j++){ int i = t + j*256; float v = src[i]; pl[i] = v; ls += v; }
  #pragma unroll
  for (int o = 32; o; o >>= 1) ls += __shfl_xor(ls, o);
  if ((t & 63) == 0) red[t >> 6] = ls;
  __syncthreads();
  if (t == 0) wsp[OFF_P1 + (size_t)b*512 + cin] = (red[0]+red[1]+red[2]+red[3]) * (1.f/2304.f);
  if (t < 9){
    int ry = t/3, rx = t%3; float sm = 0.f;
    for (int yy = 0; yy < 16; yy++)
      for (int xx = 0; xx < 16; xx++) sm += pl[(ry*16+yy)*48 + rx*16+xx];
    wsp[OFF_P3 + ((size_t)b*9 + t)*512 + cin] = sm * (1.f/256.f);
  } else if (t < 34){
    int j = t - 9; int ry = j/5, rx = j%5;
    int hs = (ry*48)/5, he = ((ry+1)*48+4)/5, cs = (rx*48)/5, ce = ((rx+1)*48+4)/5;
    float sm = 0.f;
    for (int yy = hs; yy < he; yy++)
      for (int xx = cs; xx < ce; xx++) sm += pl[yy*48+xx];
    wsp[OFF_P5 + ((size_t)b*25 + j)*512 + cin] = sm / (float)((he-hs)*(ce-cs));
  }
}

// ---------------- K3: s = relu(Wgc3.x+b) + fused QKV, X staged via global_load_lds ----------------
__global__ __launch_bounds__(256) void k_sgemm_qkv(const float* __restrict__ x,
    const float* __restrict__ w, const float* __restrict__ bias,
    const float* __restrict__ wq, const float* __restrict__ bq,
    const float* __restrict__ wk, const float* __restrict__ bk,
    const float* __restrict__ wv, const float* __restrict__ bv,
    float* __restrict__ wsp){
  __shared__ __align__(16) float wt[64][66];     // [k][row]
  __shared__ __align__(16) float xs[64][32];     // [k][col] staged X chunk
  __shared__ __align__(16) float s_lds[64][36];  // [chan][col]
  __shared__ float wq_lds[80][64];
  __shared__ float bqkv[80];
  int cb = blockIdx.x;
  int b = cb / 72, hw0 = (cb - b*72)*32;
  int tid = threadIdx.x;
  int wv_ = tid >> 6, lane = tid & 63;
  for (int i = tid; i < 5120; i += 256){
    int row = i >> 6, k = i & 63;
    wq_lds[row][k] = (row < 8) ? wq[(size_t)row*64 + k]
                   : (row < 16) ? wk[(size_t)(row-8)*64 + k]
                                : wv[(size_t)(row-16)*64 + k];
  }
  if (tid < 80) bqkv[tid] = (tid < 8) ? bq[tid] : (tid < 16) ? bk[tid-8] : bv[tid-16];
  int sr = tid >> 2, sseg = tid & 3;
  int cc0 = (tid & 7)*4, r0 = (tid >> 3)*2;
  const float* xb = x + (size_t)b*512*2304 + hw0;
  float acc[2][4] = {};
  for (int kc = 0; kc < 512; kc += 64){
    __syncthreads();
    {
      int rr0 = wv_*16 + (lane >> 3);
      const float* g0 = xb + (size_t)(kc + rr0)*2304 + (lane & 7)*4;
      const float* g1 = xb + (size_t)(kc + rr0 + 8)*2304 + (lane & 7)*4;
      GLOAD_LDS(g0, &xs[wv_*16][0]);
      GLOAD_LDS(g1, &xs[wv_*16 + 8][0]);
    }
    #pragma unroll
    for (int i = 0; i < 16; i += 4){
      float4 v = *(const float4*)(w + (size_t)sr*512 + kc + sseg*16 + i);
      wt[sseg*16+i+0][sr]=v.x; wt[sseg*16+i+1][sr]=v.y;
      wt[sseg*16+i+2][sr]=v.z; wt[sseg*16+i+3][sr]=v.w;
    }
    __syncthreads();
    #pragma unroll 4
    for (int k = 0; k < 64; k++){
      float2 wv2 = *(const float2*)&wt[k][r0];
      float4 xv = *(const float4*)&xs[k][cc0];
      acc[0][0]+=wv2.x*xv.x; acc[0][1]+=wv2.x*xv.y; acc[0][2]+=wv2.x*xv.z; acc[0][3]+=wv2.x*xv.w;
      acc[1][0]+=wv2.y*xv.x; acc[1][1]+=wv2.y*xv.y; acc[1][2]+=wv2.y*xv.z; acc[1][3]+=wv2.y*xv.w;
    }
  }
  #pragma unroll
  for (int i = 0; i < 2; i++){
    float bi = bias[r0+i];
    float4 o;
    o.x = fmaxf(acc[i][0]+bi, 0.f); o.y = fmaxf(acc[i][1]+bi, 0.f);
    o.z = fmaxf(acc[i][2]+bi, 0.f); o.w = fmaxf(acc[i][3]+bi, 0.f);
    *(float4*)(wsp + OFF_S + ((size_t)b*64 + r0+i)*2304 + hw0 + cc0) = o;
    *(float4*)&s_lds[r0+i][cc0] = o;
  }
  __syncthreads();
  int col = tid & 31, rgrp = tid >> 5;
  float a2[10];
  #pragma unroll
  for (int i = 0; i < 10; i++) a2[i] = bqkv[rgrp*10 + i];
  for (int k = 0; k < 64; k++){
    float sv = s_lds[k][col];
    #pragma unroll
    for (int i = 0; i < 10; i++) a2[i] += wq_lds[rgrp*10 + i][k]*sv;
  }
  __hip_bfloat16* Vb = reinterpret_cast<__hip_bfloat16*>(wsp + OFF_V);
  int hw = hw0 + col;
  #pragma unroll
  for (int i = 0; i < 10; i++){
    int r = rgrp*10 + i;
    if (r < 8)       wsp[OFF_Q + (size_t)b*18432 + (size_t)r*2304 + hw] = a2[i];
    else if (r < 16) wsp[OFF_K + (size_t)b*18432 + (size_t)(r-8)*2304 + hw] = a2[i];
    else             Vb[(size_t)b*147456 + (size_t)(r-16)*2304 + hw] = __float2bfloat16(a2[i]);
  }
}

// ---------------- LAUNCH C: attn (0..287) + gcconv (288..357) ----------------
__device__ void attn_body(int blk, float* __restrict__ wsp, const float* __restrict__ gamma,
                          float (*qs)[8], unsigned short (*plds)[2312],
                          float (*redM)[16], float (*redS)[16], float (*tile)[68]){
  int mb = (blk % 144) * 16;
  int b  = blk / 144;
  int t = threadIdx.x;
  int w = t >> 6, lane = t & 63;
  int arow = lane & 15, kg = lane >> 4;
  const float* Qp = wsp + OFF_Q + (size_t)b*18432;
  const float* Kp = wsp + OFF_K + (size_t)b*18432;
  if (t < 128) qs[t>>3][t&7] = Qp[(size_t)(t&7)*2304 + mb + (t>>3)];
  __syncthreads();
  float k8[9][8];
  #pragma unroll
  for (int j = 0; j < 9; j++){
    int n = j*256 + t;
    #pragma unroll
    for (int c = 0; c < 8; c++) k8[j][c] = Kp[(size_t)c*2304 + n];
  }
  float mx[16], ssum[16];
  #pragma unroll
  for (int m = 0; m < 16; m++){
    float q0=qs[m][0], q1=qs[m][1], q2=qs[m][2], q3=qs[m][3];
    float q4=qs[m][4], q5=qs[m][5], q6=qs[m][6], q7=qs[m][7];
    float lmx = -1e30f, ls = 0.f;
    #pragma unroll
    for (int j = 0; j < 9; j++){
      float l = q0*k8[j][0]+q1*k8[j][1]+q2*k8[j][2]+q3*k8[j][3]
              + q4*k8[j][4]+q5*k8[j][5]+q6*k8[j][6]+q7*k8[j][7];
      __half hv = __float2half(l);
      plds[m][j*256 + t] = __half_as_ushort(hv);
      float mo = lmx;
      lmx = fmaxf(lmx, l);
      ls = ls*__expf(mo - lmx) + __expf(l - lmx);
    }
    mx[m] = lmx; ssum[m] = ls;
  }
  #pragma unroll
  for (int m = 0; m < 16; m++){
    float M = mx[m], S = ssum[m];
    #pragma unroll
    for (int off = 32; off; off >>= 1){
      float oM = __shfl_xor(M, off), oS = __shfl_xor(S, off);
      float nM = fmaxf(M, oM);
      S = S*__expf(M - nM) + oS*__expf(oM - nM);
      M = nM;
    }
    if (lane == 0){ redM[w][m] = M; redS[w][m] = S; }
  }
  __syncthreads();
  float Mf[16], invS[16];
  #pragma unroll
  for (int m = 0; m < 16; m++){
    float M0 = redM[0][m], M1 = redM[1][m], M2 = redM[2][m], M3 = redM[3][m];
    float M = fmaxf(fmaxf(M0, M1), fmaxf(M2, M3));
    float S = redS[0][m]*__expf(M0-M) + redS[1][m]*__expf(M1-M)
            + redS[2][m]*__expf(M2-M) + redS[3][m]*__expf(M3-M);
    Mf[m] = M; invS[m] = 1.f/S;
  }
  const short* Vb = (const short*)(wsp + OFF_V) + (size_t)b*147456 + (size_t)(w*16 + arow)*2304;
  f32x4 acc = {0.f, 0.f, 0.f, 0.f};
  for (int j = 0; j < 9; j++){
    int n = j*256 + t;
    #pragma unroll
    for (int m = 0; m < 16; m++){
      float l = __half2float(__ushort_as_half(plds[m][n]));
      float p = __expf(l - Mf[m]) * invS[m];
      __hip_bfloat16 pb = __float2bfloat16(p);
      plds[m][n] = *(unsigned short*)&pb;
    }
    __syncthreads();
    #pragma unroll
    for (int ks = 0; ks < 8; ks++){
      int nb = j*256 + ks*32 + kg*8;
      short8 a  = *(const short8*)&plds[arow][nb];
      short8 bv = *(const short8*)(Vb + nb);
      acc = __builtin_amdgcn_mfma_f32_16x16x32_bf16(a, bv, acc, 0, 0, 0);
    }
  }
  #pragma unroll
  for (int r = 0; r < 4; r++) tile[kg*4 + r][w*16 + arow] = acc[r];
  __syncthreads();
  int c = t >> 2, mq = t & 3;
  float g = gamma[0];
  const float* Sp = wsp + OFF_S + (size_t)b*147456 + (size_t)c*2304 + mb + mq*4;
  float4 s4 = *(const float4*)Sp;
  float4 o;
  o.x = g*tile[mq*4+0][c] + s4.x;
  o.y = g*tile[mq*4+1][c] + s4.y;
  o.z = g*tile[mq*4+2][c] + s4.z;
  o.w = g*tile[mq*4+3][c] + s4.w;
  *(float4*)(wsp + OFF_SA + (size_t)b*147456 + (size_t)c*2304 + mb + mq*4) = o;
}

__device__ void gcconv_body(int col,
    const float* __restrict__ w0, const float* __restrict__ b0,
    const float* __restrict__ w1, const float* __restrict__ b1,
    const float* __restrict__ w2, const float* __restrict__ b2,
    float* __restrict__ wsp){
  const float* w; const float* bias; const float* pool; float* dst;
  if (col < 2){ w = w0; bias = b0; pool = wsp + OFF_P1 + (size_t)col*512; dst = wsp + OFF_G0 + (size_t)col*64; }
  else if (col < 20){ int c = col-2;  w = w1; bias = b1; pool = wsp + OFF_P3 + (size_t)c*512; dst = wsp + OFF_G1 + (size_t)c*64; }
  else              { int c = col-20; w = w2; bias = b2; pool = wsp + OFF_P5 + (size_t)c*512; dst = wsp + OFF_G2 + (size_t)c*64; }
  int t = threadIdx.x; int r = t >> 2, qd = t & 3;
  const float* wr = w + (size_t)r*512 + qd*128;
  const float* pr = pool + qd*128;
  float acc = 0.f;
  #pragma unroll 8
  for (int k = 0; k < 128; k += 4){
    float4 wv = *(const float4*)(wr + k); float4 pv = *(const float4*)(pr + k);
    acc += wv.x*pv.x + wv.y*pv.y + wv.z*pv.z + wv.w*pv.w;
  }
  acc += __shfl_xor(acc, 1); acc += __shfl_xor(acc, 2);
  if (qd == 0) dst[r] = fmaxf(acc + bias[r], 0.f);
}

__global__ __launch_bounds__(256) void k_attn_gc(float* __restrict__ wsp, const float* __restrict__ gamma,
    const float* __restrict__ w0, const float* __restrict__ b0,
    const float* __restrict__ w1, const float* __restrict__ b1,
    const float* __restrict__ w2, const float* __restrict__ b2){
  __shared__ float qs[16][8];
  __shared__ __align__(16) unsigned short plds[16][2312];
  __shared__ float redM[4][16], redS[4][16];
  __shared__ float tile[16][68];
  int bx = blockIdx.x;
  if (bx < 288) attn_body(bx, wsp, gamma, qs, plds, redM, redS, tile);
  else          gcconv_body(bx - 288, w0, b0, w1, b1, w2, b2, wsp);
}

// ---------------- K8+K9 merged: gcup (0..3455) + gap (3456..3583) ----------------
__device__ void gcup_body(int u, float* __restrict__ wsp){
  int px = (u % 9)*256 + threadIdx.x;      // 0..2303
  int pb = u / 9;                          // t*128 + b*64 + c
  int c = pb & 63, b = (pb >> 6) & 1, t = pb >> 7;
  int oy = px / 48, ox = px - oy*48;
  int ps; const float* g;
  if (t == 0){ ps = 1; g = wsp + OFF_G0 + (size_t)b*64; }
  else if (t == 1){ ps = 3; g = wsp + OFF_G1 + (size_t)b*9*64; }
  else { ps = 5; g = wsp + OFF_G2 + (size_t)b*25*64; }
  float scale = (ps - 1) / 47.f;
  float cy = oy*scale, cx = ox*scale;
  int y0 = (int)cy, x0 = (int)cx;
  float wy = cy - y0, wx = cx - x0;
  int y1 = min(y0+1, ps-1), x1 = min(x0+1, ps-1);
  float a  = g[(y0*ps+x0)*64 + c], bq = g[(y0*ps+x1)*64 + c];
  float cc = g[(y1*ps+x0)*64 + c], d  = g[(y1*ps+x1)*64 + c];
  float v = (a*(1.f-wx) + bq*wx)*(1.f-wy) + (cc*(1.f-wx) + d*wx)*wy;
  wsp[OFF_GC + (((size_t)t*2 + b)*64 + c)*2304 + px] = v;
}

__device__ void gap_body(int blk, float* __restrict__ wsp){
  __shared__ float red[4];
  int c = blk & 63, b = blk >> 6;          // 128 blocks
  const float* src = wsp + OFF_SA + ((size_t)b*64 + c)*2304;
  float s = 0.f;
  for (int i = threadIdx.x; i < 2304; i += 256) s += src[i];
  #pragma unroll
  for (int o = 32; o; o >>= 1) s += __shfl_xor(s, o);
  if ((threadIdx.x & 63) == 0) red[threadIdx.x >> 6] = s;
  __syncthreads();
  if (threadIdx.x == 0)
    wsp[OFF_MEAN + (size_t)b*64 + c] = (red[0]+red[1]+red[2]+red[3]) * (1.f/2304.f);
}

__global__ __launch_bounds__(256) void k_gcup_gap(float* __restrict__ wsp){
  int bx = blockIdx.x;
  if (bx < 3456) gcup_body(bx, wsp);
  else           gap_body(bx - 3456, wsp);
}

// ---------------- K10: SE (gc means analytic from G) ----------------
__global__ __launch_bounds__(256) void k_se(
    const float* __restrict__ w_se1, const float* __restrict__ w_se2,
    const float* __restrict__ w_se3, const float* __restrict__ w_se4,
    float* __restrict__ wsp){
  int b = blockIdx.x; int tid = threadIdx.x;
  int g = tid >> 6, c = tid & 63;
  __shared__ float mean_lds[4][64];
  float mv;
  if (g == 0){
    mv = wsp[OFF_MEAN + (size_t)b*64 + c];
  } else if (g == 3){
    mv = wsp[OFF_G0 + (size_t)b*64 + c];
  } else if (g == 2){
    float w3[3] = {0.f,0.f,0.f};
    for (int o = 0; o < 48; o++){
      float cc = o*(2.f/47.f); int i0 = (int)cc; float f = cc - i0;
      int i1 = min(i0+1, 2);
      w3[i0] += 1.f - f; w3[i1] += f;
    }
    float s = 0.f;
    for (int sy = 0; sy < 3; sy++)
      for (int sx = 0; sx < 3; sx++)
        s += w3[sy]*w3[sx]*wsp[OFF_G1 + ((size_t)b*9 + sy*3 + sx)*64 + c];
    mv = s * (1.f/(48.f*48.f));
  } else {
    float w5[5] = {0.f,0.f,0.f,0.f,0.f};
    for (int o = 0; o < 48; o++){
      float cc = o*(4.f/47.f); int i0 = (int)cc; float f = cc - i0;
      int i1 = min(i0+1, 4);
      w5[i0] += 1.f - f; w5[i1] += f;
    }
    float s = 0.f;
    for (int sy = 0; sy < 5; sy++)
      for (int sx = 0; sx < 5; sx++)
        s += w5[sy]*w5[sx]*wsp[OFF_G2 + ((size_t)b*25 + sy*5 + sx)*64 + c];
    mv = s * (1.f/(48.f*48.f));
  }
  mean_lds[g][c] = mv;
  __syncthreads();
  const float* w = (g == 0) ? w_se1 : (g == 1) ? w_se2 : (g == 2) ? w_se3 : w_se4;
  float acc = 0.f;
  for (int j = 0; j < 64; j++) acc += w[(size_t)c*64 + j]*mean_lds[g][j];
  float sg = 1.f / (1.f + __expf(-acc));
  __shared__ float sh[4][64];
  sh[g][c] = sg;
  __syncthreads();
  float a0 = sh[0][c], a1 = sh[1][c], a2 = sh[2][c], a3 = sh[3][c];
  float mxv = fmaxf(fmaxf(a0, a1), fmaxf(a2, a3));
  float e = __expf(sg - mxv);
  float sum = __expf(a0-mxv) + __expf(a1-mxv) + __expf(a2-mxv) + __expf(a3-mxv);
  wsp[OFF_WGT + ((size_t)b*4 + g)*64 + c] = e / sum;
}

// ---------------- K12: out-head GEMMs, wgt folded, X staged via global_load_lds ----------------
__global__ __launch_bounds__(256) void k_outgemm(
    const float* __restrict__ w0, const float* __restrict__ b0,
    const float* __restrict__ w1, const float* __restrict__ b1,
    const float* __restrict__ w2, const float* __restrict__ b2,
    const float* __restrict__ w3, const float* __restrict__ b3,
    float* __restrict__ wsp){
  __shared__ __align__(16) float wt[64][68];
  __shared__ __align__(16) float xsh[64][64];   // staged activation chunk (16 KB, linear)
  __shared__ float wg[256];
  int cb = blockIdx.x, rb = blockIdx.y;
  int b = cb / 36, hw0 = (cb - b*36)*64;
  const float* wsrc; const float* bsrc; size_t dstoff; int dstC; int row0;
  if (rb < 4){ wsrc = w0 + (size_t)rb*64*256; bsrc = b0 + rb*64; dstoff = OFF_Y0; dstC = 256; row0 = rb*64; }
  else if (rb < 6){ wsrc = w1 + (size_t)(rb-4)*64*256; bsrc = b1 + (rb-4)*64; dstoff = OFF_Y1; dstC = 128; row0 = (rb-4)*64; }
  else if (rb == 6){ wsrc = w2; bsrc = b2; dstoff = OFF_Y2; dstC = 64; row0 = 0; }
  else { wsrc = w3; bsrc = b3; dstoff = OFF_Y3; dstC = 64; row0 = 0; }
  int tid = threadIdx.x;
  int wv_ = tid >> 6, lane = tid & 63;
  wg[tid] = wsp[OFF_WGT + (size_t)b*256 + tid];
  int sr = tid >> 2, sseg = tid & 3;
  int cc0 = (tid & 15)*4, r0 = (tid >> 4)*4;
  float acc[4][4] = {};
  for (int kc = 0; kc < 256; kc += 64){
    __syncthreads();
    {
      int gidx = kc >> 6;
      size_t srcbase = (gidx < 3) ? OFF_GC + ((size_t)(gidx*2 + b))*147456
                                  : OFF_SA + (size_t)b*147456;
      const float* gb = wsp + srcbase + hw0 + (lane & 15)*4;
      int rr = wv_*16 + (lane >> 4);
      #pragma unroll
      for (int i = 0; i < 4; i++)
        GLOAD_LDS(gb + (size_t)(rr + i*4)*2304, &xsh[wv_*16 + i*4][0]);
    }
    #pragma unroll
    for (int i = 0; i < 16; i += 4){
      float4 v = *(const float4*)(wsrc + (size_t)sr*256 + kc + sseg*16 + i);
      int kl = sseg*16 + i;
      wt[kl+0][sr]=v.x*wg[kc+kl+0]; wt[kl+1][sr]=v.y*wg[kc+kl+1];
      wt[kl+2][sr]=v.z*wg[kc+kl+2]; wt[kl+3][sr]=v.w*wg[kc+kl+3];
    }
    __syncthreads();
    #pragma unroll 4
    for (int k = 0; k < 64; k++){
      float4 wv = *(const float4*)&wt[k][r0];
      float4 xv = *(const float4*)&xsh[k][cc0];
      acc[0][0]+=wv.x*xv.x; acc[0][1]+=wv.x*xv.y; acc[0][2]+=wv.x*xv.z; acc[0][3]+=wv.x*xv.w;
      acc[1][0]+=wv.y*xv.x; acc[1][1]+=wv.y*xv.y; acc[1][2]+=wv.y*xv.z; acc[1][3]+=wv.y*xv.w;
      acc[2][0]+=wv.z*xv.x; acc[2][1]+=wv.z*xv.y; acc[2][2]+=wv.z*xv.z; acc[2][3]+=wv.z*xv.w;
      acc[3][0]+=wv.w*xv.x; acc[3][1]+=wv.w*xv.y; acc[3][2]+=wv.w*xv.z; acc[3][3]+=wv.w*xv.w;
    }
  }
  #pragma unroll
  for (int i = 0; i < 4; i++){
    float bi = bsrc[r0+i];
    float4 o;
    o.x = fmaxf(acc[i][0]+bi, 0.f); o.y = fmaxf(acc[i][1]+bi, 0.f);
    o.z = fmaxf(acc[i][2]+bi, 0.f); o.w = fmaxf(acc[i][3]+bi, 0.f);
    *(float4*)(wsp + dstoff + ((size_t)b*dstC + row0 + r0 + i)*2304 + hw0 + cc0) = o;
  }
}

// ---------------- K13: upsample, LDS row-band + contiguous nt stores ----------------
template<int SC, int RPB, int NR>
__device__ __forceinline__ void up_band(int bi, const float* __restrict__ src,
                                        float* __restrict__ dst, float (*srow)[48]){
  constexpr int OW = 48*SC, OH = 48*SC, OW4 = OW/4;
  constexpr float inv = 1.0f/SC;
  constexpr int BANDS = OH/RPB;
  int pc = bi / BANDS, band = bi - pc*BANDS;
  int r0b = band * RPB;
  const float* sp = src + (size_t)pc * 2304;
  int y0min = (int)fmaxf((r0b + 0.5f)*inv - 0.5f, 0.f);
  int t = threadIdx.x;
  for (int i = t; i < NR*48; i += 256){
    int r = i / 48, cc = i - r*48;
    srow[r][cc] = sp[min(y0min + r, 47)*48 + cc];
  }
  __syncthreads();
  float* dbase = dst + (size_t)pc*OH*OW + (size_t)r0b*OW;
  #pragma unroll
  for (int p = 0; p < 3; p++){
    int local = p*256 + t;                 // f4 index within band (row-major)
    int lrow = local / OW4;
    int q = local - lrow*OW4;
    int oy = r0b + lrow;
    float cy = fminf(fmaxf((oy + 0.5f)*inv - 0.5f, 0.f), 47.f);
    int y0 = (int)cy; float wy = cy - y0;
    int y1 = min(y0 + 1, 47);
    const float* s0 = srow[min(y0 - y0min, NR-1)];
    const float* s1 = srow[min(y1 - y0min, NR-1)];
    float ov[4];
    #pragma unroll
    for (int i = 0; i < 4; i++){
      float cx = fminf(fmaxf((q*4 + i + 0.5f)*inv - 0.5f, 0.f), 47.f);
      int x0 = (int)cx; float wx = cx - x0;
      int x1 = min(x0 + 1, 47);
      float a = s0[x0] + (s0[x1] - s0[x0])*wx;
      float b = s1[x0] + (s1[x1] - s1[x0])*wx;
      ov[i] = a + (b - a)*wy;
    }
    f32x4 o; o[0]=ov[0]; o[1]=ov[1]; o[2]=ov[2]; o[3]=ov[3];
    __builtin_nontemporal_store(o, (f32x4*)(dbase + (size_t)local*4));
  }
}

__global__ __launch_bounds__(256) void k_upsample_all(const float* __restrict__ wsp, float* __restrict__ out){
  __shared__ float srow[18][48];
  int b = blockIdx.x;
  if (b < 1536)        up_band<2,32,18>(b,         wsp + OFF_Y0, out,            srow);
  else if (b < 4608)   up_band<4,16,6> (b - 1536,  wsp + OFF_Y1, out + 4718592,  srow);
  else if (b < 10752)  up_band<8,8,3>  (b - 4608,  wsp + OFF_Y2, out + 14155776, srow);
  else                 up_band<16,4,3> (b - 10752, wsp + OFF_Y3, out + 33030144, srow);
}

// ---------------- launcher ----------------
extern "C" void kernel_launch(void* const* d_in, const int* in_sizes, int n_in,
                              void* d_out, int out_size, void* d_ws, size_t ws_size,
                              hipStream_t stream){
  const float* x     = (const float*)d_in[0];
  const float* w_gc0 = (const float*)d_in[1];
  const float* b_gc0 = (const float*)d_in[2];
  const float* w_gc1 = (const float*)d_in[3];
  const float* b_gc1 = (const float*)d_in[4];
  const float* w_gc2 = (const float*)d_in[5];
  const float* b_gc2 = (const float*)d_in[6];
  const float* w_gc3 = (const float*)d_in[7];
  const float* b_gc3 = (const float*)d_in[8];
  const float* w_q   = (const float*)d_in[9];
  const float* b_q   = (const float*)d_in[10];
  const float* w_k   = (const float*)d_in[11];
  const float* b_k   = (const float*)d_in[12];
  const float* w_v   = (const float*)d_in[13];
  const float* b_v   = (const float*)d_in[14];
  const float* gamma = (const float*)d_in[15];
  const float* w_se1 = (const float*)d_in[16];
  const float* w_se2 = (const float*)d_in[17];
  const float* w_se3 = (const float*)d_in[18];
  const float* w_se4 = (const float*)d_in[19];
  const float* w_out0 = (const float*)d_in[20];
  const float* b_out0 = (const float*)d_in[21];
  const float* w_out1 = (const float*)d_in[22];
  const float* b_out1 = (const float*)d_in[23];
  const float* w_out2 = (const float*)d_in[24];
  const float* b_out2 = (const float*)d_in[25];
  const float* w_out3 = (const float*)d_in[26];
  const float* b_out3 = (const float*)d_in[27];
  float* wsp = (float*)d_ws;
  float* out = (float*)d_out;

  k_pool     <<<1024, 256, 0, stream>>>(x, wsp);
  k_sgemm_qkv<<<144,  256, 0, stream>>>(x, w_gc3, b_gc3, w_q,b_q,w_k,b_k,w_v,b_v, wsp);
  k_attn_gc  <<<358,  256, 0, stream>>>(wsp, gamma, w_gc0,b_gc0,w_gc1,b_gc1,w_gc2,b_gc2);
  k_gcup_gap <<<3584, 256, 0, stream>>>(wsp);
  k_se       <<<2,    256, 0, stream>>>(w_se1,w_se2,w_se3,w_se4, wsp);
  k_outgemm  <<<dim3(72,8), 256, 0, stream>>>(w_out0,b_out0,w_out1,b_out1,w_out2,b_out2,w_out3,b_out3, wsp);
  k_upsample_all<<<35328, 256, 0, stream>>>(wsp, out);
}